// Round 1
// baseline (258.492 us; speedup 1.0000x reference)
//
#include <hip/hip_runtime.h>
#include <stdint.h>

#define S    2304
#define CHN  256
#define BATCH 4

typedef __attribute__((ext_vector_type(8))) short bf16x8;
typedef __attribute__((ext_vector_type(4))) float f32x4;
typedef unsigned short u16;

__device__ __forceinline__ u16 f2bf(float f) {
  union { float f; uint32_t u; } v; v.f = f;
  uint32_t u = v.u;
  u += 0x7fffu + ((u >> 16) & 1u);
  return (u16)(u >> 16);
}
__device__ __forceinline__ float bf2f(u16 h) {
  union { uint32_t u; float f; } v; v.u = ((uint32_t)h) << 16;
  return v.f;
}

// ---------------- kernel 0: convert weights to bf16 ----------------
__global__ void k_prep(const float* __restrict__ wq, const float* __restrict__ wo,
                       u16* __restrict__ wq_bf, u16* __restrict__ wo_bf) {
  int i = blockIdx.x * 256 + threadIdx.x;           // grid 1024 -> 262144 threads
  if (i < 768 * 256) wq_bf[i] = f2bf(wq[i]);
  int j = i - 768 * 256;
  if (j >= 0 && j < 256 * 256) wo_bf[j] = f2bf(wo[j]);
}

// ---------------- kernel 1: GroupNorm stats (one block per (b,g)) ----------------
__global__ void k_gnstats(const float* __restrict__ x, float2* __restrict__ stats) {
  int bg = blockIdx.x;                               // 64 blocks, 1024 threads
  const float4* p = (const float4*)(x + (size_t)bg * 36864);
  float s = 0.f, ss = 0.f;
  for (int i = threadIdx.x; i < 9216; i += 1024) {
    float4 v = p[i];
    s  += v.x + v.y + v.z + v.w;
    ss += v.x * v.x + v.y * v.y + v.z * v.z + v.w * v.w;
  }
  int lane = threadIdx.x & 63, wv = threadIdx.x >> 6;
  for (int m = 1; m < 64; m <<= 1) { s += __shfl_xor(s, m, 64); ss += __shfl_xor(ss, m, 64); }
  __shared__ float rs[16], rss[16];
  if (lane == 0) { rs[wv] = s; rss[wv] = ss; }
  __syncthreads();
  if (threadIdx.x == 0) {
    float S_ = 0.f, SS = 0.f;
    for (int i = 0; i < 16; ++i) { S_ += rs[i]; SS += rss[i]; }
    float mean = S_ / 36864.f;
    float var  = SS / 36864.f - mean * mean;
    stats[bg] = make_float2(mean, rsqrtf(var + 1e-5f));
  }
}

// ---------------- kernel 2: normalize + transpose-write normed^T [n][c] bf16 ----------------
__global__ void k_gnnorm(const float* __restrict__ x, const float* __restrict__ w,
                         const float* __restrict__ bias, const float2* __restrict__ stats,
                         u16* __restrict__ nt) {
  int bid = blockIdx.x;                              // 144 blocks = 4 b * 36 s-tiles
  int b = bid / 36, blk = bid % 36;
  int t = threadIdx.x;
  int ni = t & 63, cq = t >> 6;                      // 64 rows x 4 c-quarters
  int s = blk * 64 + ni;
  int n = b * S + s;
  u16* dst = nt + (size_t)n * 256 + cq * 64;
  for (int c8 = 0; c8 < 8; ++c8) {
    bf16x8 v;
    for (int e = 0; e < 8; ++e) {
      int c = cq * 64 + c8 * 8 + e;
      float2 stg = stats[b * 16 + (c >> 4)];
      float val = x[(size_t)(b * 256 + c) * S + s];
      float xn = (val - stg.x) * stg.y * w[c] + bias[c];
      v[e] = (short)f2bf(xn);
    }
    *(bf16x8*)(dst + c8 * 8) = v;
  }
}

// ---------------- kernel 3/6: bf16 MFMA GEMM, A[M][256] @ B[n][256]^T ----------------
// mode 0: write bf16 out_bf[o*9216+n]   (QKV projection)
// mode 1: write fp32 d_out with bias + residual (out projection)
__global__ __launch_bounds__(256) void k_gemm(const u16* __restrict__ A,
                                              const u16* __restrict__ Bm,
                                              u16* __restrict__ out_bf,
                                              float* __restrict__ out_f,
                                              const float* __restrict__ bias,
                                              const float* __restrict__ resid,
                                              int mode) {
  __shared__ __align__(16) u16 As[128 * 32];
  __shared__ __align__(16) u16 Bs[128 * 32];
  int tid = threadIdx.x, lane = tid & 63, w = tid >> 6;
  int wr = w >> 1, wc = w & 1;
  int cb = lane & 15, q4 = lane >> 4;
  int m0 = blockIdx.y * 128, n0 = blockIdx.x * 128;

  f32x4 zero4 = {0.f, 0.f, 0.f, 0.f};
  f32x4 acc[4][4];
  for (int i = 0; i < 4; ++i) for (int j = 0; j < 4; ++j) acc[i][j] = zero4;

  for (int k0 = 0; k0 < 256; k0 += 32) {
    __syncthreads();
    for (int it = 0; it < 2; ++it) {
      int idx = it * 256 + tid;                      // 512 16B chunks per array
      int row = idx >> 2, ch = idx & 3;
      *(bf16x8*)&As[row * 32 + ch * 8] = *(const bf16x8*)&A [(size_t)(m0 + row) * 256 + k0 + ch * 8];
      *(bf16x8*)&Bs[row * 32 + ch * 8] = *(const bf16x8*)&Bm[(size_t)(n0 + row) * 256 + k0 + ch * 8];
    }
    __syncthreads();
    bf16x8 af[4], bfr[4];
    for (int i = 0; i < 4; ++i)
      af[i]  = *(const bf16x8*)&As[(wr * 64 + i * 16 + cb) * 32 + 8 * q4];
    for (int j = 0; j < 4; ++j)
      bfr[j] = *(const bf16x8*)&Bs[(wc * 64 + j * 16 + cb) * 32 + 8 * q4];
    for (int i = 0; i < 4; ++i)
      for (int j = 0; j < 4; ++j)
        acc[i][j] = __builtin_amdgcn_mfma_f32_16x16x32_bf16(af[i], bfr[j], acc[i][j], 0, 0, 0);
  }

  for (int i = 0; i < 4; ++i)
    for (int j = 0; j < 4; ++j)
      for (int r = 0; r < 4; ++r) {
        int o = m0 + wr * 64 + i * 16 + q4 * 4 + r;
        int n = n0 + wc * 64 + j * 16 + cb;
        float v = acc[i][j][r];
        if (mode == 0) {
          out_bf[(size_t)o * 9216 + n] = f2bf(v);
        } else {
          int b = n / S, s2 = n % S;
          size_t gi = (size_t)(b * 256 + o) * S + s2;
          out_f[gi] = v + bias[o] + resid[gi];
        }
      }
}

// ---------------- kernel 4: transpose q,k channels -> qkt[n][head*64 + (q:0..31 | k:32..63)] ----------------
__global__ void k_tq(const u16* __restrict__ qkv, u16* __restrict__ qkt) {
  __shared__ u16 tile[64 * 65];
  int n0 = blockIdx.x * 64, c0 = blockIdx.y * 64;    // grid (144, 8)
  for (int idx = threadIdx.x; idx < 4096; idx += 256) {
    int ci = idx >> 6, ni = idx & 63;
    int c = c0 + ci;
    int o = (c >> 6) * 96 + (c & 63);                // q: +d, k: +32+d within head
    tile[ci * 65 + ni] = qkv[(size_t)o * 9216 + n0 + ni];
  }
  __syncthreads();
  for (int idx = threadIdx.x; idx < 4096; idx += 256) {
    int ni = idx >> 6, ci = idx & 63;
    float f = bf2f(tile[ci * 65 + ni]);
    if (ci < 32) f *= 0.0625f;                       // fold 1/sqrt(C)=1/16 into Q (exact pow2)
    qkt[(size_t)(n0 + ni) * 512 + c0 + ci] = f2bf(f);
  }
}

// ---------------- kernel 5: flash attention, bf16 MFMA ----------------
// Q,K from qkt[n][512]; V from qkv[o][n]; out -> ot[n][256] (c = head*32+d)
__global__ __launch_bounds__(256) void k_attn(const u16* __restrict__ qkt,
                                              const u16* __restrict__ qkv,
                                              u16* __restrict__ ot) {
  __shared__ __align__(16) u16 Ks[64 * 40];          // [key][d] stride 40
  __shared__ __align__(16) u16 Vs[32 * 72];          // [d][key] stride 72
  __shared__ __align__(16) u16 Ps[4 * 16 * 72];      // per-wave P [q][t] stride 72
  int tid = threadIdx.x, lane = tid & 63, w = tid >> 6;
  int cb = lane & 15, q4 = lane >> 4;
  int qt0 = blockIdx.x * 64;                         // 36 q-tiles
  int bh = blockIdx.y;                               // 32 = 4 b * 8 heads
  int b = bh >> 3, h = bh & 7;

  // per-wave Q fragment: 16 queries x 32 d (K=32 exactly one MFMA K-step)
  bf16x8 qf = *(const bf16x8*)&qkt[(size_t)(b * S + qt0 + w * 16 + cb) * 512 + h * 64 + 8 * q4];

  f32x4 zero4 = {0.f, 0.f, 0.f, 0.f};
  f32x4 of[2]; of[0] = zero4; of[1] = zero4;
  float m_r[4], l_r[4];
  for (int r = 0; r < 4; ++r) { m_r[r] = -1e30f; l_r[r] = 0.f; }

  const u16* kbase = qkt + (size_t)(b * S) * 512 + h * 64 + 32;
  const u16* vbase = qkv + (size_t)(h * 96 + 64) * 9216 + (size_t)b * S;
  u16* pw = Ps + w * 1152;                           // 16*72

  for (int t0 = 0; t0 < S; t0 += 64) {
    __syncthreads();
    {                                                // stage K (64x32) and V (32x64)
      int row = tid >> 2, ch = tid & 3;
      *(bf16x8*)&Ks[row * 40 + ch * 8] = *(const bf16x8*)&kbase[(size_t)(t0 + row) * 512 + ch * 8];
      int d = tid >> 3, ch2 = tid & 7;
      *(bf16x8*)&Vs[d * 72 + ch2 * 8] = *(const bf16x8*)&vbase[(size_t)d * 9216 + t0 + ch2 * 8];
    }
    __syncthreads();

    // scores: 16 queries x 64 keys (4 N-frags), Q pre-scaled by 1/16
    f32x4 sc[4];
    for (int j = 0; j < 4; ++j) {
      bf16x8 kf = *(const bf16x8*)&Ks[(j * 16 + cb) * 40 + 8 * q4];
      sc[j] = __builtin_amdgcn_mfma_f32_16x16x32_bf16(qf, kf, zero4, 0, 0, 0);
    }

    // online softmax per row r (row = q4*4+r), reduce across the 16 lanes of the row
    float al[4];
    for (int r = 0; r < 4; ++r) {
      float mx = fmaxf(fmaxf(sc[0][r], sc[1][r]), fmaxf(sc[2][r], sc[3][r]));
      for (int msk = 1; msk < 16; msk <<= 1) mx = fmaxf(mx, __shfl_xor(mx, msk, 64));
      float mn = fmaxf(m_r[r], mx);
      float a = __expf(m_r[r] - mn);
      float rsum = 0.f;
      for (int j = 0; j < 4; ++j) {
        float p = __expf(sc[j][r] - mn);
        sc[j][r] = p;
        rsum += p;
      }
      for (int msk = 1; msk < 16; msk <<= 1) rsum += __shfl_xor(rsum, msk, 64);
      m_r[r] = mn;
      l_r[r] = l_r[r] * a + rsum;
      al[r] = a;
    }
    for (int jd = 0; jd < 2; ++jd)
      for (int r = 0; r < 4; ++r) of[jd][r] *= al[r];

    // P -> bf16 -> per-wave LDS (row = query, col = key)
    for (int j = 0; j < 4; ++j)
      for (int r = 0; r < 4; ++r)
        pw[(q4 * 4 + r) * 72 + j * 16 + cb] = f2bf(sc[j][r]);
    asm volatile("s_waitcnt lgkmcnt(0)" ::: "memory");  // same-wave cross-lane LDS RAW

    // PV: O[16q x 32d] += P(16x64) @ V^T(64x32)
    for (int kk = 0; kk < 2; ++kk) {
      bf16x8 pa = *(const bf16x8*)&pw[cb * 72 + kk * 32 + 8 * q4];
      for (int jd = 0; jd < 2; ++jd) {
        bf16x8 vb = *(const bf16x8*)&Vs[(jd * 16 + cb) * 72 + kk * 32 + 8 * q4];
        of[jd] = __builtin_amdgcn_mfma_f32_16x16x32_bf16(pa, vb, of[jd], 0, 0, 0);
      }
    }
  }

  for (int jd = 0; jd < 2; ++jd)
    for (int r = 0; r < 4; ++r) {
      int sq = qt0 + w * 16 + q4 * 4 + r;
      int c = h * 32 + jd * 16 + cb;
      ot[(size_t)(b * S + sq) * 256 + c] = f2bf(of[jd][r] * (1.f / l_r[r]));
    }
}

// ---------------- host launch ----------------
extern "C" void kernel_launch(void* const* d_in, const int* in_sizes, int n_in,
                              void* d_out, int out_size, void* d_ws, size_t ws_size,
                              hipStream_t stream) {
  const float* input = (const float*)d_in[0];
  const float* gnw   = (const float*)d_in[1];
  const float* gnb   = (const float*)d_in[2];
  const float* wqkv  = (const float*)d_in[3];
  const float* wout  = (const float*)d_in[4];
  const float* bout  = (const float*)d_in[5];
  float* out = (float*)d_out;
  char* ws = (char*)d_ws;

  size_t o_wq  = 0;                                   // 768*256*2
  size_t o_wo  = o_wq + (size_t)768 * 256 * 2;        // 256*256*2
  size_t o_st  = o_wo + (size_t)256 * 256 * 2;        // 64*8 (+pad)
  size_t o_nt  = o_st + 1024;                         // 9216*256*2
  size_t o_qkv = o_nt + (size_t)9216 * 256 * 2;       // 768*9216*2
  size_t o_qkt = o_qkv + (size_t)768 * 9216 * 2;      // 9216*512*2
  size_t o_ot  = o_qkt + (size_t)9216 * 512 * 2;      // 9216*256*2

  u16*    wq_bf = (u16*)(ws + o_wq);
  u16*    wo_bf = (u16*)(ws + o_wo);
  float2* stats = (float2*)(ws + o_st);
  u16*    nt    = (u16*)(ws + o_nt);
  u16*    qkvb  = (u16*)(ws + o_qkv);
  u16*    qkt   = (u16*)(ws + o_qkt);
  u16*    otb   = (u16*)(ws + o_ot);

  k_prep<<<1024, 256, 0, stream>>>(wqkv, wout, wq_bf, wo_bf);
  k_gnstats<<<64, 1024, 0, stream>>>(input, stats);
  k_gnnorm<<<144, 256, 0, stream>>>(input, gnw, gnb, stats, nt);
  k_gemm<<<dim3(72, 6), 256, 0, stream>>>(wq_bf, nt, qkvb, nullptr, nullptr, nullptr, 0);
  k_tq<<<dim3(144, 8), 256, 0, stream>>>(qkvb, qkt);
  k_attn<<<dim3(36, 32), 256, 0, stream>>>(qkt, qkvb, otb);
  k_gemm<<<dim3(72, 2), 256, 0, stream>>>(wo_bf, otb, nullptr, out, bout, input, 1);
}

// Round 2
// 195.100 us; speedup vs baseline: 1.3249x; 1.3249x over previous
//
#include <hip/hip_runtime.h>
#include <hip/hip_bf16.h>
#include <stdint.h>

#define S    2304
#define CHN  256
#define BATCH 4

typedef __attribute__((ext_vector_type(8))) short bf16x8;
typedef __attribute__((ext_vector_type(4))) float f32x4;
typedef __attribute__((ext_vector_type(2))) uint32_t u32x2;
typedef unsigned short u16;

__device__ __forceinline__ u16 f2bf(float f) {
  union { float f; uint32_t u; } v; v.f = f;
  uint32_t u = v.u;
  u += 0x7fffu + ((u >> 16) & 1u);
  return (u16)(u >> 16);
}
__device__ __forceinline__ float bf2f(u16 h) {
  union { uint32_t u; float f; } v; v.u = ((uint32_t)h) << 16;
  return v.f;
}
__device__ __forceinline__ uint32_t pk_bf16(float a, float b) {
  union { __hip_bfloat162 h; uint32_t u; } cv;
  cv.h = __float22bfloat162_rn(make_float2(a, b));
  return cv.u;
}

// ---------------- kernel 0: convert weights to bf16 ----------------
__global__ void k_prep(const float* __restrict__ wq, const float* __restrict__ wo,
                       u16* __restrict__ wq_bf, u16* __restrict__ wo_bf) {
  int i = blockIdx.x * 256 + threadIdx.x;
  if (i < 768 * 256) wq_bf[i] = f2bf(wq[i]);
  int j = i - 768 * 256;
  if (j >= 0 && j < 256 * 256) wo_bf[j] = f2bf(wo[j]);
}

// ---------------- kernel 1: GroupNorm stats ----------------
__global__ void k_gnstats(const float* __restrict__ x, float2* __restrict__ stats) {
  int bg = blockIdx.x;
  const float4* p = (const float4*)(x + (size_t)bg * 36864);
  float s = 0.f, ss = 0.f;
  for (int i = threadIdx.x; i < 9216; i += 1024) {
    float4 v = p[i];
    s  += v.x + v.y + v.z + v.w;
    ss += v.x * v.x + v.y * v.y + v.z * v.z + v.w * v.w;
  }
  int lane = threadIdx.x & 63, wv = threadIdx.x >> 6;
  for (int m = 1; m < 64; m <<= 1) { s += __shfl_xor(s, m, 64); ss += __shfl_xor(ss, m, 64); }
  __shared__ float rs[16], rss[16];
  if (lane == 0) { rs[wv] = s; rss[wv] = ss; }
  __syncthreads();
  if (threadIdx.x == 0) {
    float S_ = 0.f, SS = 0.f;
    for (int i = 0; i < 16; ++i) { S_ += rs[i]; SS += rss[i]; }
    float mean = S_ / 36864.f;
    float var  = SS / 36864.f - mean * mean;
    stats[bg] = make_float2(mean, rsqrtf(var + 1e-5f));
  }
}

// ---------------- kernel 2: normalize + transpose-write normed^T [n][c] bf16 ----------------
__global__ void k_gnnorm(const float* __restrict__ x, const float* __restrict__ w,
                         const float* __restrict__ bias, const float2* __restrict__ stats,
                         u16* __restrict__ nt) {
  int bid = blockIdx.x;
  int b = bid / 36, blk = bid % 36;
  int t = threadIdx.x;
  int ni = t & 63, cq = t >> 6;
  int s = blk * 64 + ni;
  int n = b * S + s;
  u16* dst = nt + (size_t)n * 256 + cq * 64;
  for (int c8 = 0; c8 < 8; ++c8) {
    bf16x8 v;
    for (int e = 0; e < 8; ++e) {
      int c = cq * 64 + c8 * 8 + e;
      float2 stg = stats[b * 16 + (c >> 4)];
      float val = x[(size_t)(b * 256 + c) * S + s];
      float xn = (val - stg.x) * stg.y * w[c] + bias[c];
      v[e] = (short)f2bf(xn);
    }
    *(bf16x8*)(dst + c8 * 8) = v;
  }
}

// ---------------- kernel 3/6: bf16 MFMA GEMM, A[M][256] @ B[n][256]^T ----------------
__global__ __launch_bounds__(256) void k_gemm(const u16* __restrict__ A,
                                              const u16* __restrict__ Bm,
                                              u16* __restrict__ out_bf,
                                              float* __restrict__ out_f,
                                              const float* __restrict__ bias,
                                              const float* __restrict__ resid,
                                              int mode) {
  __shared__ __align__(16) u16 As[128 * 32];
  __shared__ __align__(16) u16 Bs[128 * 32];
  int tid = threadIdx.x, lane = tid & 63, w = tid >> 6;
  int wr = w >> 1, wc = w & 1;
  int cb = lane & 15, q4 = lane >> 4;
  int m0 = blockIdx.y * 128, n0 = blockIdx.x * 128;

  f32x4 zero4 = {0.f, 0.f, 0.f, 0.f};
  f32x4 acc[4][4];
  for (int i = 0; i < 4; ++i) for (int j = 0; j < 4; ++j) acc[i][j] = zero4;

  for (int k0 = 0; k0 < 256; k0 += 32) {
    __syncthreads();
    for (int it = 0; it < 2; ++it) {
      int idx = it * 256 + tid;
      int row = idx >> 2, ch = idx & 3;
      *(bf16x8*)&As[row * 32 + ch * 8] = *(const bf16x8*)&A [(size_t)(m0 + row) * 256 + k0 + ch * 8];
      *(bf16x8*)&Bs[row * 32 + ch * 8] = *(const bf16x8*)&Bm[(size_t)(n0 + row) * 256 + k0 + ch * 8];
    }
    __syncthreads();
    bf16x8 af[4], bfr[4];
    for (int i = 0; i < 4; ++i)
      af[i]  = *(const bf16x8*)&As[(wr * 64 + i * 16 + cb) * 32 + 8 * q4];
    for (int j = 0; j < 4; ++j)
      bfr[j] = *(const bf16x8*)&Bs[(wc * 64 + j * 16 + cb) * 32 + 8 * q4];
    for (int i = 0; i < 4; ++i)
      for (int j = 0; j < 4; ++j)
        acc[i][j] = __builtin_amdgcn_mfma_f32_16x16x32_bf16(af[i], bfr[j], acc[i][j], 0, 0, 0);
  }

  for (int i = 0; i < 4; ++i)
    for (int j = 0; j < 4; ++j)
      for (int r = 0; r < 4; ++r) {
        int o = m0 + wr * 64 + i * 16 + q4 * 4 + r;
        int n = n0 + wc * 64 + j * 16 + cb;
        float v = acc[i][j][r];
        if (mode == 0) {
          out_bf[(size_t)o * 9216 + n] = f2bf(v);
        } else {
          int b = n / S, s2 = n % S;
          size_t gi = (size_t)(b * 256 + o) * S + s2;
          out_f[gi] = v + bias[o] + resid[gi];
        }
      }
}

// ---------------- kernel 4: transpose q,k -> qkt[n][head*64 + (q:0..31 | k:32..63)] ----------------
// Q pre-scaled by log2(e)/16 so attention can use native exp2.
__global__ void k_tq(const u16* __restrict__ qkv, u16* __restrict__ qkt) {
  __shared__ u16 tile[64 * 65];
  int n0 = blockIdx.x * 64, c0 = blockIdx.y * 64;
  for (int idx = threadIdx.x; idx < 4096; idx += 256) {
    int ci = idx >> 6, ni = idx & 63;
    int c = c0 + ci;
    int o = (c >> 6) * 96 + (c & 63);
    tile[ci * 65 + ni] = qkv[(size_t)o * 9216 + n0 + ni];
  }
  __syncthreads();
  for (int idx = threadIdx.x; idx < 4096; idx += 256) {
    int ni = idx >> 6, ci = idx & 63;
    float f = bf2f(tile[ci * 65 + ni]);
    if (ci < 32) f *= 0.09016844005556021f;          // (1/16) * log2(e)
    qkt[(size_t)(n0 + ni) * 512 + c0 + ci] = f2bf(f);
  }
}

// ---------------- kernel 5: flash attention, swapped-QK, no-max softmax ----------------
// Per wave: 32 queries. Block: 4 waves = 128 queries. K-tile = 64 keys.
// K,V staged via global_load_lds (linear LDS dest, pre-swizzled global source);
// reads apply the same XOR swizzle -> <=2-way bank conflicts.
__global__ __launch_bounds__(256) void k_attn(const u16* __restrict__ qkt,
                                              const u16* __restrict__ qkv,
                                              u16* __restrict__ ot) {
  __shared__ __align__(16) u16 Ks[64 * 32];          // [key][d], 64B rows, swizzled chunks
  __shared__ __align__(16) u16 Vd[32 * 64];          // [d][key], 128B rows, swizzled chunks
  __shared__ __align__(16) u16 Ps[4][32 * 64];       // per-wave P [q][key], 128B rows, swizzled

  int tid = threadIdx.x, lane = tid & 63, w = tid >> 6;
  int cb = lane & 15, g4 = lane >> 4;
  int q0 = blockIdx.x * 128 + w * 32;                // 18 q-blocks
  int bh = blockIdx.y;                               // 32 = 4 b * 8 heads
  int b = bh >> 3, h = bh & 7;

  const u16* kbase = qkt + (size_t)(b * S) * 512 + h * 64 + 32;
  const u16* vbase = qkv + (size_t)(h * 96 + 64) * 9216 + (size_t)b * S;
  u16* Pw = &Ps[w][0];

  // Q fragments (B-operand): Q[q=16*qf+cb][k=8*g4..], 2 frags for 32 queries
  bf16x8 qf[2];
  for (int i = 0; i < 2; ++i)
    qf[i] = *(const bf16x8*)&qkt[(size_t)(b * S + q0 + 16 * i + cb) * 512 + h * 64 + 8 * g4];

  f32x4 zero4 = {0.f, 0.f, 0.f, 0.f};
  f32x4 acc_o[2][2];
  for (int i = 0; i < 2; ++i) for (int j = 0; j < 2; ++j) acc_o[i][j] = zero4;
  float l[2] = {0.f, 0.f};

  int xk = (cb ^ (cb >> 2)) & 3;                     // K-read swizzle (row bits fold to cb)
  int sw7 = cb & 7;                                  // V/P swizzle key

  // staging source addresses (pre-swizzled global chunk so linear LDS + swizzled read match)
  int krow = tid >> 2, kch = (tid & 3) ^ ((krow ^ (krow >> 2)) & 3);
  int vrow = tid >> 3, vch = (tid & 7) ^ (vrow & 7);
  const u16* gK0 = kbase + (size_t)krow * 512 + kch * 8;
  const u16* gV0 = vbase + (size_t)vrow * 9216 + vch * 8;
  char* ldsK = (char*)&Ks[0] + ((tid >> 6) << 10);   // wave-uniform base; HW adds lane*16
  char* ldsV = (char*)&Vd[0] + ((tid >> 6) << 10);

  for (int t0 = 0; t0 < S; t0 += 64) {
    __syncthreads();
    __builtin_amdgcn_global_load_lds((const __attribute__((address_space(1))) void*)(gK0 + (size_t)t0 * 512),
                                     (__attribute__((address_space(3))) void*)ldsK, 16, 0, 0);
    __builtin_amdgcn_global_load_lds((const __attribute__((address_space(1))) void*)(gV0 + t0),
                                     (__attribute__((address_space(3))) void*)ldsV, 16, 0, 0);
    asm volatile("s_waitcnt vmcnt(0)" ::: "memory");
    __syncthreads();

    // K frags (A-operand): key rows 16*kf+cb, k-chunk g4 (swizzled)
    bf16x8 kf[4];
    for (int k4 = 0; k4 < 4; ++k4)
      kf[k4] = *(const bf16x8*)&Ks[(16 * k4 + cb) * 32 + (g4 ^ xk) * 8];

    // scores: D[key][q] per (kf, qf)
    f32x4 pacc[4][2];
    for (int k4 = 0; k4 < 4; ++k4)
      for (int qi = 0; qi < 2; ++qi)
        pacc[k4][qi] = __builtin_amdgcn_mfma_f32_16x16x32_bf16(kf[k4], qf[qi], zero4, 0, 0, 0);

    // p = exp2(s) (log2e folded into Q), accumulate l, pack to bf16, store P
    for (int qi = 0; qi < 2; ++qi) {
      float lacc = 0.f;
      for (int k4 = 0; k4 < 4; ++k4) {
        f32x4 p = pacc[k4][qi];
        float e0 = __builtin_amdgcn_exp2f(p[0]);
        float e1 = __builtin_amdgcn_exp2f(p[1]);
        float e2 = __builtin_amdgcn_exp2f(p[2]);
        float e3 = __builtin_amdgcn_exp2f(p[3]);
        lacc += (e0 + e1) + (e2 + e3);
        u32x2 pk = { pk_bf16(e0, e1), pk_bf16(e2, e3) };
        // P[q=16qi+cb][key = 16*k4 + 4*g4 + 0..3]; chunk (2k4 + g4/2) ^ sw7, half g4&1
        int idx = (16 * qi + cb) * 64 + (((2 * k4 + (g4 >> 1)) ^ sw7) << 3) + ((g4 & 1) << 2);
        *(u32x2*)&Pw[idx] = pk;
      }
      l[qi] += lacc;
    }

    // PV: A = P[q][key] (row=cb=q), B = V[d][key] (col=cb=d)
    for (int qi = 0; qi < 2; ++qi) {
      bf16x8 pa[2];
      for (int kk = 0; kk < 2; ++kk)
        pa[kk] = *(const bf16x8*)&Pw[(16 * qi + cb) * 64 + (((4 * kk + g4) ^ sw7) << 3)];
      for (int jd = 0; jd < 2; ++jd) {
        for (int kk = 0; kk < 2; ++kk) {
          bf16x8 vb = *(const bf16x8*)&Vd[(16 * jd + cb) * 64 + (((4 * kk + g4) ^ sw7) << 3)];
          acc_o[qi][jd] = __builtin_amdgcn_mfma_f32_16x16x32_bf16(pa[kk], vb, acc_o[qi][jd], 0, 0, 0);
        }
      }
    }
  }

  // finish l: sum across g4 groups (keys mod 16 partition), then 1/l per O-row
  float linv[2];
  for (int qi = 0; qi < 2; ++qi) {
    float v = l[qi];
    v += __shfl_xor(v, 16, 64);
    v += __shfl_xor(v, 32, 64);
    linv[qi] = __builtin_amdgcn_rcpf(v);
  }
  for (int qi = 0; qi < 2; ++qi)
    for (int r = 0; r < 4; ++r) {
      float li = __shfl(linv[qi], ((lane >> 4) << 2) | r, 64);   // l for q-row 16qi+4*g4+r
      int sq = q0 + 16 * qi + 4 * g4 + r;
      for (int jd = 0; jd < 2; ++jd) {
        int c = h * 32 + 16 * jd + cb;
        ot[(size_t)(b * S + sq) * 256 + c] = f2bf(acc_o[qi][jd][r] * li);
      }
    }
}

// ---------------- host launch ----------------
extern "C" void kernel_launch(void* const* d_in, const int* in_sizes, int n_in,
                              void* d_out, int out_size, void* d_ws, size_t ws_size,
                              hipStream_t stream) {
  const float* input = (const float*)d_in[0];
  const float* gnw   = (const float*)d_in[1];
  const float* gnb   = (const float*)d_in[2];
  const float* wqkv  = (const float*)d_in[3];
  const float* wout  = (const float*)d_in[4];
  const float* bout  = (const float*)d_in[5];
  float* out = (float*)d_out;
  char* ws = (char*)d_ws;

  size_t o_wq  = 0;
  size_t o_wo  = o_wq + (size_t)768 * 256 * 2;
  size_t o_st  = o_wo + (size_t)256 * 256 * 2;
  size_t o_nt  = o_st + 1024;
  size_t o_qkv = o_nt + (size_t)9216 * 256 * 2;
  size_t o_qkt = o_qkv + (size_t)768 * 9216 * 2;
  size_t o_ot  = o_qkt + (size_t)9216 * 512 * 2;

  u16*    wq_bf = (u16*)(ws + o_wq);
  u16*    wo_bf = (u16*)(ws + o_wo);
  float2* stats = (float2*)(ws + o_st);
  u16*    nt    = (u16*)(ws + o_nt);
  u16*    qkvb  = (u16*)(ws + o_qkv);
  u16*    qkt   = (u16*)(ws + o_qkt);
  u16*    otb   = (u16*)(ws + o_ot);

  k_prep<<<1024, 256, 0, stream>>>(wqkv, wout, wq_bf, wo_bf);
  k_gnstats<<<64, 1024, 0, stream>>>(input, stats);
  k_gnnorm<<<144, 256, 0, stream>>>(input, gnw, gnb, stats, nt);
  k_gemm<<<dim3(72, 6), 256, 0, stream>>>(wq_bf, nt, qkvb, nullptr, nullptr, nullptr, 0);
  k_tq<<<dim3(144, 8), 256, 0, stream>>>(qkvb, qkt);
  k_attn<<<dim3(18, 32), 256, 0, stream>>>(qkt, qkvb, otb);
  k_gemm<<<dim3(72, 2), 256, 0, stream>>>(wo_bf, otb, nullptr, out, bout, input, 1);
}

// Round 3
// 190.190 us; speedup vs baseline: 1.3591x; 1.0258x over previous
//
#include <hip/hip_runtime.h>
#include <hip/hip_bf16.h>
#include <stdint.h>

#define S    2304
#define CHN  256
#define BATCH 4

typedef __attribute__((ext_vector_type(8))) short bf16x8;
typedef __attribute__((ext_vector_type(4))) float f32x4;
typedef __attribute__((ext_vector_type(2))) uint32_t u32x2;
typedef unsigned short u16;

#define AS1 __attribute__((address_space(1)))
#define AS3 __attribute__((address_space(3)))
#define GLDS(gptr, lptr) __builtin_amdgcn_global_load_lds((const AS1 void*)(gptr), (AS3 void*)(lptr), 16, 0, 0)

__device__ __forceinline__ u16 f2bf(float f) {
  union { float f; uint32_t u; } v; v.f = f;
  uint32_t u = v.u;
  u += 0x7fffu + ((u >> 16) & 1u);
  return (u16)(u >> 16);
}
__device__ __forceinline__ float bf2f(u16 h) {
  union { uint32_t u; float f; } v; v.u = ((uint32_t)h) << 16;
  return v.f;
}
__device__ __forceinline__ uint32_t pk_bf16(float a, float b) {
  union { __hip_bfloat162 h; uint32_t u; } cv;
  cv.h = __float22bfloat162_rn(make_float2(a, b));
  return cv.u;
}

// ---------------- kernel 0: convert weights to bf16 ----------------
__global__ void k_prep(const float* __restrict__ wq, const float* __restrict__ wo,
                       u16* __restrict__ wq_bf, u16* __restrict__ wo_bf) {
  int i = blockIdx.x * 256 + threadIdx.x;
  if (i < 768 * 256) wq_bf[i] = f2bf(wq[i]);
  int j = i - 768 * 256;
  if (j >= 0 && j < 256 * 256) wo_bf[j] = f2bf(wo[j]);
}

// ---------------- kernel 1: GroupNorm stats ----------------
__global__ void k_gnstats(const float* __restrict__ x, float2* __restrict__ stats) {
  int bg = blockIdx.x;
  const float4* p = (const float4*)(x + (size_t)bg * 36864);
  float s = 0.f, ss = 0.f;
  for (int i = threadIdx.x; i < 9216; i += 1024) {
    float4 v = p[i];
    s  += v.x + v.y + v.z + v.w;
    ss += v.x * v.x + v.y * v.y + v.z * v.z + v.w * v.w;
  }
  int lane = threadIdx.x & 63, wv = threadIdx.x >> 6;
  for (int m = 1; m < 64; m <<= 1) { s += __shfl_xor(s, m, 64); ss += __shfl_xor(ss, m, 64); }
  __shared__ float rs[16], rss[16];
  if (lane == 0) { rs[wv] = s; rss[wv] = ss; }
  __syncthreads();
  if (threadIdx.x == 0) {
    float S_ = 0.f, SS = 0.f;
    for (int i = 0; i < 16; ++i) { S_ += rs[i]; SS += rss[i]; }
    float mean = S_ / 36864.f;
    float var  = SS / 36864.f - mean * mean;
    stats[bg] = make_float2(mean, rsqrtf(var + 1e-5f));
  }
}

// ---------------- kernel 2: normalize + transpose-write normed^T [n][c] bf16 ----------------
// 576 blocks (4x parallelism of before), one stats load per thread.
__global__ void k_gnnorm(const float* __restrict__ x, const float* __restrict__ w,
                         const float* __restrict__ bias, const float2* __restrict__ stats,
                         u16* __restrict__ nt) {
  int bid = blockIdx.x;                              // 576 = 4b * 36sblk * 4cq
  int b = bid / 144, r = bid % 144;
  int sblk = r >> 2, cq = r & 3;
  int t = threadIdx.x;
  int ni = t & 63, cgrp = t >> 6;
  int s = sblk * 64 + ni;
  int cbase = cq * 64 + cgrp * 16;
  float2 stg = stats[b * 16 + (cbase >> 4)];         // 16 channels per group; constant here
  bf16x8 v0, v1;
  #pragma unroll
  for (int e = 0; e < 16; ++e) {
    int c = cbase + e;
    float val = x[(size_t)(b * 256 + c) * S + s];
    float xn = (val - stg.x) * stg.y * w[c] + bias[c];
    if (e < 8) v0[e] = (short)f2bf(xn); else v1[e - 8] = (short)f2bf(xn);
  }
  u16* dst = nt + (size_t)(b * S + s) * 256 + cbase;
  *(bf16x8*)dst = v0;
  *(bf16x8*)(dst + 8) = v1;
}

// ---------------- kernel 3/6: bf16 MFMA GEMM, m97-style ----------------
// A[M][256] @ B[n][256]^T, 128x128 tile, BK=32, global_load_lds + 2-phase dbuf.
__global__ __launch_bounds__(256) void k_gemm(const u16* __restrict__ A,
                                              const u16* __restrict__ Bm,
                                              u16* __restrict__ out_bf,
                                              float* __restrict__ out_f,
                                              const float* __restrict__ bias,
                                              const float* __restrict__ resid,
                                              int mode) {
  __shared__ __align__(16) u16 As[2][128 * 32];
  __shared__ __align__(16) u16 Bs[2][128 * 32];
  int tid = threadIdx.x, lane = tid & 63, w = tid >> 6;
  int wr = w >> 1, wc = w & 1;
  int cb = lane & 15, q4 = lane >> 4;
  int m0 = blockIdx.y * 128, n0 = blockIdx.x * 128;

  // staging addressing: idx = it*256 + tid -> row = idx>>2 (it=1 -> +64), ch = tid&3
  int r0 = tid >> 2, ch0 = tid & 3;
  const u16* gA0 = A  + (size_t)(m0 + r0) * 256 + ch0 * 8;
  const u16* gA1 = gA0 + 64 * 256;
  const u16* gB0 = Bm + (size_t)(n0 + r0) * 256 + ch0 * 8;
  const u16* gB1 = gB0 + 64 * 256;
  char* lA = (char*)&As[0][0] + (w << 10);           // wave-uniform; HW adds lane*16
  char* lB = (char*)&Bs[0][0] + (w << 10);

  #define STAGE_G(buf, k0) do {                      \
    GLDS(gA0 + (k0), lA + (buf) * 8192);             \
    GLDS(gA1 + (k0), lA + (buf) * 8192 + 4096);      \
    GLDS(gB0 + (k0), lB + (buf) * 8192);             \
    GLDS(gB1 + (k0), lB + (buf) * 8192 + 4096);      \
  } while (0)

  f32x4 zero4 = {0.f, 0.f, 0.f, 0.f};
  f32x4 acc[4][4];
  for (int i = 0; i < 4; ++i) for (int j = 0; j < 4; ++j) acc[i][j] = zero4;

  STAGE_G(0, 0);
  __syncthreads();                                   // drains vmcnt before first use
  for (int ks = 0; ks < 8; ++ks) {
    int cur = ks & 1;
    if (ks < 7) STAGE_G(cur ^ 1, (ks + 1) * 32);     // prefetch next K-step
    const u16* as = &As[cur][0];
    const u16* bs = &Bs[cur][0];
    bf16x8 af[4], bfr[4];
    for (int i = 0; i < 4; ++i)
      af[i]  = *(const bf16x8*)&as[(wr * 64 + i * 16 + cb) * 32 + 8 * q4];
    for (int j = 0; j < 4; ++j)
      bfr[j] = *(const bf16x8*)&bs[(wc * 64 + j * 16 + cb) * 32 + 8 * q4];
    for (int i = 0; i < 4; ++i)
      for (int j = 0; j < 4; ++j)
        acc[i][j] = __builtin_amdgcn_mfma_f32_16x16x32_bf16(af[i], bfr[j], acc[i][j], 0, 0, 0);
    __syncthreads();                                 // drains prefetch; next buf ready
  }

  for (int i = 0; i < 4; ++i)
    for (int j = 0; j < 4; ++j)
      for (int r = 0; r < 4; ++r) {
        int o = m0 + wr * 64 + i * 16 + q4 * 4 + r;
        int n = n0 + wc * 64 + j * 16 + cb;
        float v = acc[i][j][r];
        if (mode == 0) {
          out_bf[(size_t)o * 9216 + n] = f2bf(v);
        } else {
          int b = n / S, s2 = n % S;
          size_t gi = (size_t)(b * 256 + o) * S + s2;
          out_f[gi] = v + bias[o] + resid[gi];
        }
      }
  #undef STAGE_G
}

// ---------------- kernel 4: transpose q,k -> qkt[n][head*64 + (q:0..31 | k:32..63)] ----------------
__global__ void k_tq(const u16* __restrict__ qkv, u16* __restrict__ qkt) {
  __shared__ u16 tile[64 * 65];
  int n0 = blockIdx.x * 64, c0 = blockIdx.y * 64;
  for (int idx = threadIdx.x; idx < 4096; idx += 256) {
    int ci = idx >> 6, ni = idx & 63;
    int c = c0 + ci;
    int o = (c >> 6) * 96 + (c & 63);
    tile[ci * 65 + ni] = qkv[(size_t)o * 9216 + n0 + ni];
  }
  __syncthreads();
  for (int idx = threadIdx.x; idx < 4096; idx += 256) {
    int ni = idx >> 6, ci = idx & 63;
    float f = bf2f(tile[ci * 65 + ni]);
    if (ci < 32) f *= 0.09016844005556021f;          // (1/16) * log2(e)
    qkt[(size_t)(n0 + ni) * 512 + c0 + ci] = f2bf(f);
  }
}

// ---------------- kernel 5: flash attention, swapped-QK, no-max softmax, 2-phase dbuf ----------------
__global__ __launch_bounds__(256) void k_attn(const u16* __restrict__ qkt,
                                              const u16* __restrict__ qkv,
                                              u16* __restrict__ ot) {
  __shared__ __align__(16) u16 Ks[2][64 * 32];       // [key][d] swizzled chunks, dbuf
  __shared__ __align__(16) u16 Vd[2][32 * 64];       // [d][key] swizzled chunks, dbuf
  __shared__ __align__(16) u16 Ps[4][32 * 64];       // per-wave P [q][key] swizzled

  int tid = threadIdx.x, lane = tid & 63, w = tid >> 6;
  int cb = lane & 15, g4 = lane >> 4;
  int q0 = blockIdx.x * 128 + w * 32;
  int bh = blockIdx.y;
  int b = bh >> 3, h = bh & 7;

  const u16* kbase = qkt + (size_t)(b * S) * 512 + h * 64 + 32;
  const u16* vbase = qkv + (size_t)(h * 96 + 64) * 9216 + (size_t)b * S;
  u16* Pw = &Ps[w][0];

  bf16x8 qf[2];
  for (int i = 0; i < 2; ++i)
    qf[i] = *(const bf16x8*)&qkt[(size_t)(b * S + q0 + 16 * i + cb) * 512 + h * 64 + 8 * g4];

  f32x4 zero4 = {0.f, 0.f, 0.f, 0.f};
  f32x4 acc_o[2][2];
  for (int i = 0; i < 2; ++i) for (int j = 0; j < 2; ++j) acc_o[i][j] = zero4;
  float l[2] = {0.f, 0.f};

  int xk = (cb ^ (cb >> 2)) & 3;
  int sw7 = cb & 7;

  int krow = tid >> 2, kch = (tid & 3) ^ ((krow ^ (krow >> 2)) & 3);
  int vrow = tid >> 3, vch = (tid & 7) ^ (vrow & 7);
  const u16* gK0 = kbase + (size_t)krow * 512 + kch * 8;
  const u16* gV0 = vbase + (size_t)vrow * 9216 + vch * 8;
  char* ldsK = (char*)&Ks[0][0] + (w << 10);
  char* ldsV = (char*)&Vd[0][0] + (w << 10);

  #define STAGE_A(buf, t0) do {                                   \
    GLDS(gK0 + (size_t)(t0) * 512, ldsK + (buf) * 4096);           \
    GLDS(gV0 + (t0),               ldsV + (buf) * 4096);           \
  } while (0)

  STAGE_A(0, 0);
  __syncthreads();

  for (int t0 = 0; t0 < S; t0 += 64) {
    int cur = (t0 >> 6) & 1;
    if (t0 + 64 < S) STAGE_A(cur ^ 1, t0 + 64);      // prefetch next K/V tile
    const u16* KsC = &Ks[cur][0];
    const u16* VdC = &Vd[cur][0];

    bf16x8 kf[4];
    for (int k4 = 0; k4 < 4; ++k4)
      kf[k4] = *(const bf16x8*)&KsC[(16 * k4 + cb) * 32 + ((g4 ^ xk) * 8)];

    f32x4 pacc[4][2];
    __builtin_amdgcn_s_setprio(1);
    for (int k4 = 0; k4 < 4; ++k4)
      for (int qi = 0; qi < 2; ++qi)
        pacc[k4][qi] = __builtin_amdgcn_mfma_f32_16x16x32_bf16(kf[k4], qf[qi], zero4, 0, 0, 0);
    __builtin_amdgcn_s_setprio(0);

    for (int qi = 0; qi < 2; ++qi) {
      float lacc = 0.f;
      for (int k4 = 0; k4 < 4; ++k4) {
        f32x4 p = pacc[k4][qi];
        float e0 = __builtin_amdgcn_exp2f(p[0]);
        float e1 = __builtin_amdgcn_exp2f(p[1]);
        float e2 = __builtin_amdgcn_exp2f(p[2]);
        float e3 = __builtin_amdgcn_exp2f(p[3]);
        lacc += (e0 + e1) + (e2 + e3);
        u32x2 pk = { pk_bf16(e0, e1), pk_bf16(e2, e3) };
        int idx = (16 * qi + cb) * 64 + (((2 * k4 + (g4 >> 1)) ^ sw7) << 3) + ((g4 & 1) << 2);
        *(u32x2*)&Pw[idx] = pk;
      }
      l[qi] += lacc;
    }
    asm volatile("s_waitcnt lgkmcnt(0)" ::: "memory");

    __builtin_amdgcn_s_setprio(1);
    for (int qi = 0; qi < 2; ++qi) {
      bf16x8 pa[2];
      for (int kk = 0; kk < 2; ++kk)
        pa[kk] = *(const bf16x8*)&Pw[(16 * qi + cb) * 64 + (((4 * kk + g4) ^ sw7) << 3)];
      for (int jd = 0; jd < 2; ++jd)
        for (int kk = 0; kk < 2; ++kk) {
          bf16x8 vb = *(const bf16x8*)&VdC[(16 * jd + cb) * 64 + (((4 * kk + g4) ^ sw7) << 3)];
          acc_o[qi][jd] = __builtin_amdgcn_mfma_f32_16x16x32_bf16(pa[kk], vb, acc_o[qi][jd], 0, 0, 0);
        }
    }
    __builtin_amdgcn_s_setprio(0);

    __syncthreads();                                 // drains prefetch loads; swap buffers
  }

  float linv[2];
  for (int qi = 0; qi < 2; ++qi) {
    float v = l[qi];
    v += __shfl_xor(v, 16, 64);
    v += __shfl_xor(v, 32, 64);
    linv[qi] = __builtin_amdgcn_rcpf(v);
  }
  for (int qi = 0; qi < 2; ++qi)
    for (int r = 0; r < 4; ++r) {
      float li = __shfl(linv[qi], ((lane >> 4) << 2) | r, 64);
      int sq = q0 + 16 * qi + 4 * g4 + r;
      for (int jd = 0; jd < 2; ++jd) {
        int c = h * 32 + 16 * jd + cb;
        ot[(size_t)(b * S + sq) * 256 + c] = f2bf(acc_o[qi][jd][r] * li);
      }
    }
  #undef STAGE_A
}

// ---------------- host launch ----------------
extern "C" void kernel_launch(void* const* d_in, const int* in_sizes, int n_in,
                              void* d_out, int out_size, void* d_ws, size_t ws_size,
                              hipStream_t stream) {
  const float* input = (const float*)d_in[0];
  const float* gnw   = (const float*)d_in[1];
  const float* gnb   = (const float*)d_in[2];
  const float* wqkv  = (const float*)d_in[3];
  const float* wout  = (const float*)d_in[4];
  const float* bout  = (const float*)d_in[5];
  float* out = (float*)d_out;
  char* ws = (char*)d_ws;

  size_t o_wq  = 0;
  size_t o_wo  = o_wq + (size_t)768 * 256 * 2;
  size_t o_st  = o_wo + (size_t)256 * 256 * 2;
  size_t o_nt  = o_st + 1024;
  size_t o_qkv = o_nt + (size_t)9216 * 256 * 2;
  size_t o_qkt = o_qkv + (size_t)768 * 9216 * 2;
  size_t o_ot  = o_qkt + (size_t)9216 * 512 * 2;

  u16*    wq_bf = (u16*)(ws + o_wq);
  u16*    wo_bf = (u16*)(ws + o_wo);
  float2* stats = (float2*)(ws + o_st);
  u16*    nt    = (u16*)(ws + o_nt);
  u16*    qkvb  = (u16*)(ws + o_qkv);
  u16*    qkt   = (u16*)(ws + o_qkt);
  u16*    otb   = (u16*)(ws + o_ot);

  k_prep<<<1024, 256, 0, stream>>>(wqkv, wout, wq_bf, wo_bf);
  k_gnstats<<<64, 1024, 0, stream>>>(input, stats);
  k_gnnorm<<<576, 256, 0, stream>>>(input, gnw, gnb, stats, nt);
  k_gemm<<<dim3(72, 6), 256, 0, stream>>>(wq_bf, nt, qkvb, nullptr, nullptr, nullptr, 0);
  k_tq<<<dim3(144, 8), 256, 0, stream>>>(qkvb, qkt);
  k_attn<<<dim3(18, 32), 256, 0, stream>>>(qkt, qkvb, otb);
  k_gemm<<<dim3(72, 2), 256, 0, stream>>>(wo_bf, otb, nullptr, out, bout, input, 1);
}

// Round 4
// 94.389 us; speedup vs baseline: 2.7386x; 2.0149x over previous
//
#include <hip/hip_runtime.h>
#include <hip/hip_bf16.h>
#include <stdint.h>

#define S    2304
#define CHN  256
#define BATCH 4
#define QS   0.09016844005556021f   // (1/16) * log2(e)

typedef __attribute__((ext_vector_type(8))) short bf16x8;
typedef __attribute__((ext_vector_type(4))) float f32x4;
typedef __attribute__((ext_vector_type(2))) uint32_t u32x2;
typedef __attribute__((ext_vector_type(4))) unsigned short u16x4;
typedef unsigned short u16;

#define AS1 __attribute__((address_space(1)))
#define AS3 __attribute__((address_space(3)))
#define GLDS(gptr, lptr) __builtin_amdgcn_global_load_lds((const AS1 void*)(gptr), (AS3 void*)(lptr), 16, 0, 0)

__device__ __forceinline__ u16 f2bf(float f) {
  union { float f; uint32_t u; } v; v.f = f;
  uint32_t u = v.u;
  u += 0x7fffu + ((u >> 16) & 1u);
  return (u16)(u >> 16);
}
__device__ __forceinline__ float bf2f(u16 h) {
  union { uint32_t u; float f; } v; v.u = ((uint32_t)h) << 16;
  return v.f;
}
__device__ __forceinline__ uint32_t pk_bf16(float a, float b) {
  union { __hip_bfloat162 h; uint32_t u; } cv;
  cv.h = __float22bfloat162_rn(make_float2(a, b));
  return cv.u;
}

// ---------------- kernel 0: convert weights to bf16 ----------------
__global__ void k_prep(const float* __restrict__ wq, const float* __restrict__ wo,
                       u16* __restrict__ wq_bf, u16* __restrict__ wo_bf) {
  int i = blockIdx.x * 256 + threadIdx.x;
  if (i < 768 * 256) wq_bf[i] = f2bf(wq[i]);
  int j = i - 768 * 256;
  if (j >= 0 && j < 256 * 256) wo_bf[j] = f2bf(wo[j]);
}

// ---------------- kernel 1: GroupNorm stats ----------------
__global__ void k_gnstats(const float* __restrict__ x, float2* __restrict__ stats) {
  int bg = blockIdx.x;
  const float4* p = (const float4*)(x + (size_t)bg * 36864);
  float s = 0.f, ss = 0.f;
  for (int i = threadIdx.x; i < 9216; i += 1024) {
    float4 v = p[i];
    s  += v.x + v.y + v.z + v.w;
    ss += v.x * v.x + v.y * v.y + v.z * v.z + v.w * v.w;
  }
  int lane = threadIdx.x & 63, wv = threadIdx.x >> 6;
  for (int m = 1; m < 64; m <<= 1) { s += __shfl_xor(s, m, 64); ss += __shfl_xor(ss, m, 64); }
  __shared__ float rs[16], rss[16];
  if (lane == 0) { rs[wv] = s; rss[wv] = ss; }
  __syncthreads();
  if (threadIdx.x == 0) {
    float S_ = 0.f, SS = 0.f;
    for (int i = 0; i < 16; ++i) { S_ += rs[i]; SS += rss[i]; }
    float mean = S_ / 36864.f;
    float var  = SS / 36864.f - mean * mean;
    stats[bg] = make_float2(mean, rsqrtf(var + 1e-5f));
  }
}

// ---------------- kernel 2: normalize + transpose-write normed^T [n][c] bf16 ----------------
__global__ void k_gnnorm(const float* __restrict__ x, const float* __restrict__ w,
                         const float* __restrict__ bias, const float2* __restrict__ stats,
                         u16* __restrict__ nt) {
  int bid = blockIdx.x;                              // 576 = 4b * 36sblk * 4cq
  int b = bid / 144, r = bid % 144;
  int sblk = r >> 2, cq = r & 3;
  int t = threadIdx.x;
  int ni = t & 63, cgrp = t >> 6;
  int s = sblk * 64 + ni;
  int cbase = cq * 64 + cgrp * 16;
  float2 stg = stats[b * 16 + (cbase >> 4)];
  bf16x8 v0, v1;
  #pragma unroll
  for (int e = 0; e < 16; ++e) {
    int c = cbase + e;
    float val = x[(size_t)(b * 256 + c) * S + s];
    float xn = (val - stg.x) * stg.y * w[c] + bias[c];
    if (e < 8) v0[e] = (short)f2bf(xn); else v1[e - 8] = (short)f2bf(xn);
  }
  u16* dst = nt + (size_t)(b * S + s) * 256 + cbase;
  *(bf16x8*)dst = v0;
  *(bf16x8*)(dst + 8) = v1;
}

// ---------------- kernel 3: QKV GEMM + fused transpose epilogue ----------------
// A = wq_bf[768][256], B = nt[n][256]. 64M x 128N tile, grid (72, 12).
// q/k channels -> qkt[n][h*64 + oq] (packed 4-wide, q pre-scaled by QS);
// v channels   -> vt[h*32 + d][n] (scalar).
__global__ __launch_bounds__(256) void k_qkv(const u16* __restrict__ A,
                                             const u16* __restrict__ Bm,
                                             u16* __restrict__ qkt,
                                             u16* __restrict__ vt) {
  __shared__ __align__(16) u16 As[2][64 * 32];
  __shared__ __align__(16) u16 Bs[2][128 * 32];
  int tid = threadIdx.x, lane = tid & 63, w = tid >> 6;
  int wr = w >> 1, wc = w & 1;
  int cb = lane & 15, q4 = lane >> 4;
  int m0 = blockIdx.y * 64, n0 = blockIdx.x * 128;

  const u16* gA0 = A  + (size_t)(m0 + (tid >> 2)) * 256 + (tid & 3) * 8;
  const u16* gB0 = Bm + (size_t)(n0 + (tid >> 2)) * 256 + (tid & 3) * 8;
  const u16* gB1 = gB0 + 64 * 256;
  char* lA = (char*)&As[0][0] + (w << 10);
  char* lB = (char*)&Bs[0][0] + (w << 10);

  #define STAGE_Q(buf, k0) do {                      \
    GLDS(gA0 + (k0), lA + (buf) * 4096);             \
    GLDS(gB0 + (k0), lB + (buf) * 8192);             \
    GLDS(gB1 + (k0), lB + (buf) * 8192 + 4096);      \
  } while (0)

  f32x4 zero4 = {0.f, 0.f, 0.f, 0.f};
  f32x4 acc[2][4];
  for (int i = 0; i < 2; ++i) for (int j = 0; j < 4; ++j) acc[i][j] = zero4;

  STAGE_Q(0, 0);
  __syncthreads();
  for (int ks = 0; ks < 8; ++ks) {
    int cur = ks & 1;
    if (ks < 7) STAGE_Q(cur ^ 1, (ks + 1) * 32);
    const u16* as = &As[cur][0];
    const u16* bs = &Bs[cur][0];
    bf16x8 af[2], bfr[4];
    for (int i = 0; i < 2; ++i)
      af[i]  = *(const bf16x8*)&as[(wr * 32 + i * 16 + cb) * 32 + 8 * q4];
    for (int j = 0; j < 4; ++j)
      bfr[j] = *(const bf16x8*)&bs[(wc * 64 + j * 16 + cb) * 32 + 8 * q4];
    for (int i = 0; i < 2; ++i)
      for (int j = 0; j < 4; ++j)
        acc[i][j] = __builtin_amdgcn_mfma_f32_16x16x32_bf16(af[i], bfr[j], acc[i][j], 0, 0, 0);
    __syncthreads();
  }

  for (int i = 0; i < 2; ++i)
    for (int j = 0; j < 4; ++j) {
      int ob = m0 + wr * 32 + i * 16 + q4 * 4;       // quad-aligned o base
      int n  = n0 + wc * 64 + j * 16 + cb;
      int h = ob / 96, oq = ob % 96;                 // quad never straddles q/k/v regions
      if (oq < 64) {                                 // q or k -> transposed packed store
        float sc = (oq < 32) ? QS : 1.f;
        u16x4 pk;
        for (int r = 0; r < 4; ++r) pk[r] = f2bf(acc[i][j][r] * sc);
        *(u16x4*)&qkt[(size_t)n * 512 + h * 64 + oq] = pk;
      } else {                                       // v -> [d'][n]
        for (int r = 0; r < 4; ++r)
          vt[(size_t)(h * 32 + oq - 64 + r) * 9216 + n] = f2bf(acc[i][j][r]);
      }
    }
  #undef STAGE_Q
}

// ---------------- kernel 4: flash attention, 16 q/wave, XCD-swizzled ----------------
__global__ __launch_bounds__(256) void k_attn(const u16* __restrict__ qkt,
                                              const u16* __restrict__ vt,
                                              u16* __restrict__ ot) {
  __shared__ __align__(16) u16 Ks[2][64 * 32];       // [key][d] swizzled chunks, dbuf
  __shared__ __align__(16) u16 Vd[2][32 * 64];       // [d][key] swizzled chunks, dbuf
  __shared__ __align__(16) u16 Ps[4][16 * 64];       // per-wave P [q][key] swizzled

  int tid = threadIdx.x, lane = tid & 63, w = tid >> 6;
  int cb = lane & 15, g4 = lane >> 4;
  // XCD swizzle: 1152 = 8 XCD * 144; consecutive orig (same bh) -> same XCD
  int hw = blockIdx.x;
  int orig = (hw & 7) * 144 + (hw >> 3);
  int bh = orig / 36, bx = orig % 36;
  int b = bh >> 3, h = bh & 7;
  int q0 = bx * 64 + w * 16;

  const u16* kbase = qkt + (size_t)(b * S) * 512 + h * 64 + 32;
  const u16* vbase = vt + (size_t)(h * 32) * 9216 + (size_t)b * S;
  u16* Pw = &Ps[w][0];

  bf16x8 qf = *(const bf16x8*)&qkt[(size_t)(b * S + q0 + cb) * 512 + h * 64 + 8 * g4];

  f32x4 zero4 = {0.f, 0.f, 0.f, 0.f};
  f32x4 acc_o[2]; acc_o[0] = zero4; acc_o[1] = zero4;
  float l = 0.f;

  int xk = (cb ^ (cb >> 2)) & 3;
  int sw7 = cb & 7;

  int krow = tid >> 2, kch = (tid & 3) ^ ((krow ^ (krow >> 2)) & 3);
  int vrow = tid >> 3, vch = (tid & 7) ^ (vrow & 7);
  const u16* gK0 = kbase + (size_t)krow * 512 + kch * 8;
  const u16* gV0 = vbase + (size_t)vrow * 9216 + vch * 8;
  char* ldsK = (char*)&Ks[0][0] + (w << 10);
  char* ldsV = (char*)&Vd[0][0] + (w << 10);

  #define STAGE_A(buf, t0) do {                                   \
    GLDS(gK0 + (size_t)(t0) * 512, ldsK + (buf) * 4096);           \
    GLDS(gV0 + (t0),               ldsV + (buf) * 4096);           \
  } while (0)

  STAGE_A(0, 0);
  __syncthreads();

  for (int t0 = 0; t0 < S; t0 += 64) {
    int cur = (t0 >> 6) & 1;
    if (t0 + 64 < S) STAGE_A(cur ^ 1, t0 + 64);
    const u16* KsC = &Ks[cur][0];
    const u16* VdC = &Vd[cur][0];

    bf16x8 kf[4];
    for (int k4 = 0; k4 < 4; ++k4)
      kf[k4] = *(const bf16x8*)&KsC[(16 * k4 + cb) * 32 + ((g4 ^ xk) * 8)];

    f32x4 pacc[4];
    __builtin_amdgcn_s_setprio(1);
    for (int k4 = 0; k4 < 4; ++k4)
      pacc[k4] = __builtin_amdgcn_mfma_f32_16x16x32_bf16(kf[k4], qf, zero4, 0, 0, 0);
    __builtin_amdgcn_s_setprio(0);

    float lacc = 0.f;
    for (int k4 = 0; k4 < 4; ++k4) {
      f32x4 p = pacc[k4];
      float e0 = __builtin_amdgcn_exp2f(p[0]);
      float e1 = __builtin_amdgcn_exp2f(p[1]);
      float e2 = __builtin_amdgcn_exp2f(p[2]);
      float e3 = __builtin_amdgcn_exp2f(p[3]);
      lacc += (e0 + e1) + (e2 + e3);
      u32x2 pk = { pk_bf16(e0, e1), pk_bf16(e2, e3) };
      int idx = cb * 64 + (((2 * k4 + (g4 >> 1)) ^ sw7) << 3) + ((g4 & 1) << 2);
      *(u32x2*)&Pw[idx] = pk;
    }
    l += lacc;
    asm volatile("s_waitcnt lgkmcnt(0)" ::: "memory");

    __builtin_amdgcn_s_setprio(1);
    bf16x8 pa[2];
    for (int kk = 0; kk < 2; ++kk)
      pa[kk] = *(const bf16x8*)&Pw[cb * 64 + (((4 * kk + g4) ^ sw7) << 3)];
    for (int jd = 0; jd < 2; ++jd)
      for (int kk = 0; kk < 2; ++kk) {
        bf16x8 vb = *(const bf16x8*)&VdC[(16 * jd + cb) * 64 + (((4 * kk + g4) ^ sw7) << 3)];
        acc_o[jd] = __builtin_amdgcn_mfma_f32_16x16x32_bf16(pa[kk], vb, acc_o[jd], 0, 0, 0);
      }
    __builtin_amdgcn_s_setprio(0);

    __syncthreads();
  }

  float v = l;
  v += __shfl_xor(v, 16, 64);
  v += __shfl_xor(v, 32, 64);
  float linv = __builtin_amdgcn_rcpf(v);
  for (int r = 0; r < 4; ++r) {
    float li = __shfl(linv, 4 * g4 + r, 64);         // 1/l for q-row 4*g4+r (from lane cb=row)
    int sq = q0 + 4 * g4 + r;
    for (int jd = 0; jd < 2; ++jd) {
      int c = h * 32 + 16 * jd + cb;
      ot[(size_t)(b * S + sq) * 256 + c] = f2bf(acc_o[jd][r] * li);
    }
  }
  #undef STAGE_A
}

// ---------------- kernel 5: out projection + bias + residual ----------------
// A = wo_bf[256][256], B = ot[n][256]. 64M x 64N tile, grid (144, 4).
__global__ __launch_bounds__(256) void k_oproj(const u16* __restrict__ A,
                                               const u16* __restrict__ Bm,
                                               float* __restrict__ out,
                                               const float* __restrict__ bias,
                                               const float* __restrict__ resid) {
  __shared__ __align__(16) u16 As[2][64 * 32];
  __shared__ __align__(16) u16 Bs[2][64 * 32];
  int tid = threadIdx.x, lane = tid & 63, w = tid >> 6;
  int cb = lane & 15, q4 = lane >> 4;
  int m0 = blockIdx.y * 64, n0 = blockIdx.x * 64;

  const u16* gA0 = A  + (size_t)(m0 + (tid >> 2)) * 256 + (tid & 3) * 8;
  const u16* gB0 = Bm + (size_t)(n0 + (tid >> 2)) * 256 + (tid & 3) * 8;
  char* lA = (char*)&As[0][0] + (w << 10);
  char* lB = (char*)&Bs[0][0] + (w << 10);

  #define STAGE_O(buf, k0) do {                      \
    GLDS(gA0 + (k0), lA + (buf) * 4096);             \
    GLDS(gB0 + (k0), lB + (buf) * 4096);             \
  } while (0)

  f32x4 zero4 = {0.f, 0.f, 0.f, 0.f};
  f32x4 acc[4];
  for (int j = 0; j < 4; ++j) acc[j] = zero4;

  STAGE_O(0, 0);
  __syncthreads();
  for (int ks = 0; ks < 8; ++ks) {
    int cur = ks & 1;
    if (ks < 7) STAGE_O(cur ^ 1, (ks + 1) * 32);
    const u16* as = &As[cur][0];
    const u16* bs = &Bs[cur][0];
    bf16x8 af = *(const bf16x8*)&as[(w * 16 + cb) * 32 + 8 * q4];
    bf16x8 bfr[4];
    for (int j = 0; j < 4; ++j)
      bfr[j] = *(const bf16x8*)&bs[(j * 16 + cb) * 32 + 8 * q4];
    for (int j = 0; j < 4; ++j)
      acc[j] = __builtin_amdgcn_mfma_f32_16x16x32_bf16(af, bfr[j], acc[j], 0, 0, 0);
    __syncthreads();
  }

  for (int j = 0; j < 4; ++j)
    for (int r = 0; r < 4; ++r) {
      int o = m0 + w * 16 + q4 * 4 + r;
      int n = n0 + j * 16 + cb;
      int b = n / S, s2 = n % S;
      size_t gi = (size_t)(b * 256 + o) * S + s2;
      out[gi] = acc[j][r] + bias[o] + resid[gi];
    }
  #undef STAGE_O
}

// ---------------- host launch ----------------
extern "C" void kernel_launch(void* const* d_in, const int* in_sizes, int n_in,
                              void* d_out, int out_size, void* d_ws, size_t ws_size,
                              hipStream_t stream) {
  const float* input = (const float*)d_in[0];
  const float* gnw   = (const float*)d_in[1];
  const float* gnb   = (const float*)d_in[2];
  const float* wqkv  = (const float*)d_in[3];
  const float* wout  = (const float*)d_in[4];
  const float* bout  = (const float*)d_in[5];
  float* out = (float*)d_out;
  char* ws = (char*)d_ws;

  size_t o_wq  = 0;                                   // 768*256*2
  size_t o_wo  = o_wq + (size_t)768 * 256 * 2;        // 256*256*2
  size_t o_st  = o_wo + (size_t)256 * 256 * 2;        // stats
  size_t o_nt  = o_st + 1024;                         // 9216*256*2
  size_t o_qkt = o_nt + (size_t)9216 * 256 * 2;       // 9216*512*2
  size_t o_vt  = o_qkt + (size_t)9216 * 512 * 2;      // 256*9216*2
  size_t o_ot  = o_vt + (size_t)256 * 9216 * 2;       // 9216*256*2

  u16*    wq_bf = (u16*)(ws + o_wq);
  u16*    wo_bf = (u16*)(ws + o_wo);
  float2* stats = (float2*)(ws + o_st);
  u16*    nt    = (u16*)(ws + o_nt);
  u16*    qkt   = (u16*)(ws + o_qkt);
  u16*    vt    = (u16*)(ws + o_vt);
  u16*    otb   = (u16*)(ws + o_ot);

  k_prep<<<1024, 256, 0, stream>>>(wqkv, wout, wq_bf, wo_bf);
  k_gnstats<<<64, 1024, 0, stream>>>(input, stats);
  k_gnnorm<<<576, 256, 0, stream>>>(input, gnw, gnb, stats, nt);
  k_qkv<<<dim3(72, 12), 256, 0, stream>>>(wq_bf, nt, qkt, vt);
  k_attn<<<1152, 256, 0, stream>>>(qkt, vt, otb);
  k_oproj<<<dim3(144, 4), 256, 0, stream>>>(wo_bf, otb, out, bout, input);
}

// Round 5
// 93.210 us; speedup vs baseline: 2.7732x; 1.0127x over previous
//
#include <hip/hip_runtime.h>
#include <hip/hip_bf16.h>
#include <stdint.h>

#define S    2304
#define CHN  256
#define BATCH 4
#define NKEYS 1152                  // keys per split (2-way split-K)
#define QS   0.09016844005556021f   // (1/16) * log2(e)

typedef __attribute__((ext_vector_type(8))) short bf16x8;
typedef __attribute__((ext_vector_type(4))) float f32x4;
typedef __attribute__((ext_vector_type(2))) uint32_t u32x2;
typedef __attribute__((ext_vector_type(4))) unsigned short u16x4;
typedef unsigned short u16;

#define AS1 __attribute__((address_space(1)))
#define AS3 __attribute__((address_space(3)))
#define GLDS(gptr, lptr) __builtin_amdgcn_global_load_lds((const AS1 void*)(gptr), (AS3 void*)(lptr), 16, 0, 0)

__device__ __forceinline__ u16 f2bf(float f) {
  union { float f; uint32_t u; } v; v.f = f;
  uint32_t u = v.u;
  u += 0x7fffu + ((u >> 16) & 1u);
  return (u16)(u >> 16);
}
__device__ __forceinline__ float bf2f(u16 h) {
  union { uint32_t u; float f; } v; v.u = ((uint32_t)h) << 16;
  return v.f;
}
__device__ __forceinline__ uint32_t pk_bf16(float a, float b) {
  union { __hip_bfloat162 h; uint32_t u; } cv;
  cv.h = __float22bfloat162_rn(make_float2(a, b));
  return cv.u;
}

// ---------------- kernel 0: convert weights to bf16 ----------------
__global__ void k_prep(const float* __restrict__ wq, const float* __restrict__ wo,
                       u16* __restrict__ wq_bf, u16* __restrict__ wo_bf) {
  int i = blockIdx.x * 256 + threadIdx.x;
  if (i < 768 * 256) wq_bf[i] = f2bf(wq[i]);
  int j = i - 768 * 256;
  if (j >= 0 && j < 256 * 256) wo_bf[j] = f2bf(wo[j]);
}

// ---------------- kernel 1: GroupNorm stats ----------------
__global__ void k_gnstats(const float* __restrict__ x, float2* __restrict__ stats) {
  int bg = blockIdx.x;
  const float4* p = (const float4*)(x + (size_t)bg * 36864);
  float s = 0.f, ss = 0.f;
  for (int i = threadIdx.x; i < 9216; i += 1024) {
    float4 v = p[i];
    s  += v.x + v.y + v.z + v.w;
    ss += v.x * v.x + v.y * v.y + v.z * v.z + v.w * v.w;
  }
  int lane = threadIdx.x & 63, wv = threadIdx.x >> 6;
  for (int m = 1; m < 64; m <<= 1) { s += __shfl_xor(s, m, 64); ss += __shfl_xor(ss, m, 64); }
  __shared__ float rs[16], rss[16];
  if (lane == 0) { rs[wv] = s; rss[wv] = ss; }
  __syncthreads();
  if (threadIdx.x == 0) {
    float S_ = 0.f, SS = 0.f;
    for (int i = 0; i < 16; ++i) { S_ += rs[i]; SS += rss[i]; }
    float mean = S_ / 36864.f;
    float var  = SS / 36864.f - mean * mean;
    stats[bg] = make_float2(mean, rsqrtf(var + 1e-5f));
  }
}

// ---------------- kernel 2: normalize + transpose-write normed^T [n][c] bf16 ----------------
__global__ void k_gnnorm(const float* __restrict__ x, const float* __restrict__ w,
                         const float* __restrict__ bias, const float2* __restrict__ stats,
                         u16* __restrict__ nt) {
  int bid = blockIdx.x;                              // 576 = 4b * 36sblk * 4cq
  int b = bid / 144, r = bid % 144;
  int sblk = r >> 2, cq = r & 3;
  int t = threadIdx.x;
  int ni = t & 63, cgrp = t >> 6;
  int s = sblk * 64 + ni;
  int cbase = cq * 64 + cgrp * 16;
  float2 stg = stats[b * 16 + (cbase >> 4)];
  bf16x8 v0, v1;
  #pragma unroll
  for (int e = 0; e < 16; ++e) {
    int c = cbase + e;
    float val = x[(size_t)(b * 256 + c) * S + s];
    float xn = (val - stg.x) * stg.y * w[c] + bias[c];
    if (e < 8) v0[e] = (short)f2bf(xn); else v1[e - 8] = (short)f2bf(xn);
  }
  u16* dst = nt + (size_t)(b * S + s) * 256 + cbase;
  *(bf16x8*)dst = v0;
  *(bf16x8*)(dst + 8) = v1;
}

// ---------------- kernel 3: QKV GEMM + fused transpose epilogue ----------------
__global__ __launch_bounds__(256) void k_qkv(const u16* __restrict__ A,
                                             const u16* __restrict__ Bm,
                                             u16* __restrict__ qkt,
                                             u16* __restrict__ vt) {
  __shared__ __align__(16) u16 As[2][64 * 32];
  __shared__ __align__(16) u16 Bs[2][128 * 32];
  int tid = threadIdx.x, lane = tid & 63, w = tid >> 6;
  int wr = w >> 1, wc = w & 1;
  int cb = lane & 15, q4 = lane >> 4;
  int m0 = blockIdx.y * 64, n0 = blockIdx.x * 128;

  const u16* gA0 = A  + (size_t)(m0 + (tid >> 2)) * 256 + (tid & 3) * 8;
  const u16* gB0 = Bm + (size_t)(n0 + (tid >> 2)) * 256 + (tid & 3) * 8;
  const u16* gB1 = gB0 + 64 * 256;
  char* lA = (char*)&As[0][0] + (w << 10);
  char* lB = (char*)&Bs[0][0] + (w << 10);

  #define STAGE_Q(buf, k0) do {                      \
    GLDS(gA0 + (k0), lA + (buf) * 4096);             \
    GLDS(gB0 + (k0), lB + (buf) * 8192);             \
    GLDS(gB1 + (k0), lB + (buf) * 8192 + 4096);      \
  } while (0)

  f32x4 zero4 = {0.f, 0.f, 0.f, 0.f};
  f32x4 acc[2][4];
  for (int i = 0; i < 2; ++i) for (int j = 0; j < 4; ++j) acc[i][j] = zero4;

  STAGE_Q(0, 0);
  __syncthreads();
  for (int ks = 0; ks < 8; ++ks) {
    int cur = ks & 1;
    if (ks < 7) STAGE_Q(cur ^ 1, (ks + 1) * 32);
    const u16* as = &As[cur][0];
    const u16* bs = &Bs[cur][0];
    bf16x8 af[2], bfr[4];
    for (int i = 0; i < 2; ++i)
      af[i]  = *(const bf16x8*)&as[(wr * 32 + i * 16 + cb) * 32 + 8 * q4];
    for (int j = 0; j < 4; ++j)
      bfr[j] = *(const bf16x8*)&bs[(wc * 64 + j * 16 + cb) * 32 + 8 * q4];
    for (int i = 0; i < 2; ++i)
      for (int j = 0; j < 4; ++j)
        acc[i][j] = __builtin_amdgcn_mfma_f32_16x16x32_bf16(af[i], bfr[j], acc[i][j], 0, 0, 0);
    __syncthreads();
  }

  for (int i = 0; i < 2; ++i)
    for (int j = 0; j < 4; ++j) {
      int ob = m0 + wr * 32 + i * 16 + q4 * 4;
      int n  = n0 + wc * 64 + j * 16 + cb;
      int h = ob / 96, oq = ob % 96;
      if (oq < 64) {
        float sc = (oq < 32) ? QS : 1.f;
        u16x4 pk;
        for (int r = 0; r < 4; ++r) pk[r] = f2bf(acc[i][j][r] * sc);
        *(u16x4*)&qkt[(size_t)n * 512 + h * 64 + oq] = pk;
      } else {
        for (int r = 0; r < 4; ++r)
          vt[(size_t)(h * 32 + oq - 64 + r) * 9216 + n] = f2bf(acc[i][j][r]);
      }
    }
  #undef STAGE_Q
}

// ---------------- kernel 4: flash attention, split-K (2-way), 16 q/wave ----------------
// No-max softmax => partials are linear: O = sum O_i, l = sum l_i.
// Writes unnormalized bf16 O partial + f32 l partial; k_comb combines.
__global__ __launch_bounds__(256) void k_attn(const u16* __restrict__ qkt,
                                              const u16* __restrict__ vt,
                                              u16* __restrict__ otP,
                                              float* __restrict__ lsum) {
  __shared__ __align__(16) u16 Ks[2][64 * 32];       // [key][d] swizzled chunks, dbuf
  __shared__ __align__(16) u16 Vd[2][32 * 64];       // [d][key] swizzled chunks, dbuf
  __shared__ __align__(16) u16 Ps[4][16 * 64];       // per-wave P [q][key] swizzled

  int tid = threadIdx.x, lane = tid & 63, w = tid >> 6;
  int cb = lane & 15, g4 = lane >> 4;
  // XCD swizzle: 2304 = 8 XCD * 288; consecutive orig (same bh) -> same XCD
  int hw = blockIdx.x;
  int orig = (hw & 7) * 288 + (hw >> 3);
  int bh = orig / 72, rem = orig % 72;
  int qtile = rem >> 1, split = rem & 1;
  int b = bh >> 3, h = bh & 7;
  int q0 = qtile * 64 + w * 16;

  const u16* kbase = qkt + (size_t)(b * S) * 512 + h * 64 + 32 + (size_t)split * NKEYS * 512;
  const u16* vbase = vt + (size_t)(h * 32) * 9216 + (size_t)b * S + split * NKEYS;

  bf16x8 qf = *(const bf16x8*)&qkt[(size_t)(b * S + q0 + cb) * 512 + h * 64 + 8 * g4];

  f32x4 zero4 = {0.f, 0.f, 0.f, 0.f};
  f32x4 acc_o[2]; acc_o[0] = zero4; acc_o[1] = zero4;
  float l = 0.f;

  int xk = (cb ^ (cb >> 2)) & 3;
  int sw7 = cb & 7;

  // hoisted LDS addresses (buf0; buf1 = +2048 u16 = imm offset 4096B)
  const u16* p_kf[4];
  #pragma unroll
  for (int k4 = 0; k4 < 4; ++k4)
    p_kf[k4] = &Ks[0][(16 * k4 + cb) * 32 + ((g4 ^ xk) * 8)];
  u16* p_pw[4];
  #pragma unroll
  for (int k4 = 0; k4 < 4; ++k4)
    p_pw[k4] = &Ps[w][cb * 64 + (((2 * k4 + (g4 >> 1)) ^ sw7) << 3) + ((g4 & 1) << 2)];
  const u16* p_pa[2];
  #pragma unroll
  for (int kk = 0; kk < 2; ++kk)
    p_pa[kk] = &Ps[w][cb * 64 + (((4 * kk + g4) ^ sw7) << 3)];
  const u16* p_vb[2][2];
  #pragma unroll
  for (int jd = 0; jd < 2; ++jd)
    #pragma unroll
    for (int kk = 0; kk < 2; ++kk)
      p_vb[jd][kk] = &Vd[0][(16 * jd + cb) * 64 + (((4 * kk + g4) ^ sw7) << 3)];

  // staging: self-incrementing global pointers, pre-swizzled source
  int krow = tid >> 2, kch = (tid & 3) ^ ((krow ^ (krow >> 2)) & 3);
  int vrow = tid >> 3, vch = (tid & 7) ^ (vrow & 7);
  const u16* gK = kbase + (size_t)krow * 512 + kch * 8;
  const u16* gV = vbase + (size_t)vrow * 9216 + vch * 8;
  char* ldsK = (char*)&Ks[0][0] + (w << 10);
  char* ldsV = (char*)&Vd[0][0] + (w << 10);

  #define STAGE_A(buf) do {                          \
    GLDS(gK, ldsK + (buf) * 4096);                   \
    GLDS(gV, ldsV + (buf) * 4096);                   \
    gK += 64 * 512; gV += 64;                        \
  } while (0)

  #define TILE(buf, pf) do {                                                   \
    if (pf) STAGE_A(buf ^ 1);                                                  \
    bf16x8 kf[4];                                                              \
    _Pragma("unroll")                                                          \
    for (int k4 = 0; k4 < 4; ++k4)                                             \
      kf[k4] = *(const bf16x8*)(p_kf[k4] + (buf) * 2048);                      \
    f32x4 pacc[4];                                                             \
    __builtin_amdgcn_s_setprio(1);                                             \
    _Pragma("unroll")                                                          \
    for (int k4 = 0; k4 < 4; ++k4)                                             \
      pacc[k4] = __builtin_amdgcn_mfma_f32_16x16x32_bf16(kf[k4], qf, zero4, 0, 0, 0); \
    __builtin_amdgcn_s_setprio(0);                                             \
    float lacc = 0.f;                                                          \
    _Pragma("unroll")                                                          \
    for (int k4 = 0; k4 < 4; ++k4) {                                           \
      f32x4 p = pacc[k4];                                                      \
      float e0 = __builtin_amdgcn_exp2f(p[0]);                                 \
      float e1 = __builtin_amdgcn_exp2f(p[1]);                                 \
      float e2 = __builtin_amdgcn_exp2f(p[2]);                                 \
      float e3 = __builtin_amdgcn_exp2f(p[3]);                                 \
      lacc += (e0 + e1) + (e2 + e3);                                           \
      u32x2 pk = { pk_bf16(e0, e1), pk_bf16(e2, e3) };                         \
      *(u32x2*)p_pw[k4] = pk;                                                  \
    }                                                                          \
    l += lacc;                                                                 \
    asm volatile("s_waitcnt lgkmcnt(0)" ::: "memory");                         \
    __builtin_amdgcn_sched_barrier(0);                                         \
    __builtin_amdgcn_s_setprio(1);                                             \
    bf16x8 pa[2];                                                              \
    _Pragma("unroll")                                                          \
    for (int kk = 0; kk < 2; ++kk)                                             \
      pa[kk] = *(const bf16x8*)p_pa[kk];                                       \
    _Pragma("unroll")                                                          \
    for (int jd = 0; jd < 2; ++jd)                                             \
      _Pragma("unroll")                                                        \
      for (int kk = 0; kk < 2; ++kk) {                                         \
        bf16x8 vb = *(const bf16x8*)(p_vb[jd][kk] + (buf) * 2048);             \
        acc_o[jd] = __builtin_amdgcn_mfma_f32_16x16x32_bf16(pa[kk], vb, acc_o[jd], 0, 0, 0); \
      }                                                                        \
    __builtin_amdgcn_s_setprio(0);                                             \
    __syncthreads();                                                           \
  } while (0)

  STAGE_A(0);
  __syncthreads();
  for (int it = 0; it < 9; ++it) {                   // 18 tiles, unroll x2
    TILE(0, 1);
    TILE(1, it < 8);
  }

  // l partial: sum across the 4-lane key-groups -> full l(q=cb) in every lane
  float v = l;
  v += __shfl_xor(v, 16, 64);
  v += __shfl_xor(v, 32, 64);
  if (lane < 16)
    lsum[(size_t)(bh * 2 + split) * S + q0 + lane] = v;

  // unnormalized O partial -> bf16
  u16* op = otP + (size_t)split * 9216 * 256;
  for (int r = 0; r < 4; ++r) {
    int sq = q0 + 4 * g4 + r;
    for (int jd = 0; jd < 2; ++jd) {
      int c = h * 32 + 16 * jd + cb;
      op[(size_t)(b * S + sq) * 256 + c] = f2bf(acc_o[jd][r]);
    }
  }
  #undef STAGE_A
  #undef TILE
}

// ---------------- kernel 4b: combine split-K partials + normalize ----------------
__global__ void k_comb(const u16* __restrict__ otP, const float* __restrict__ lsum,
                       u16* __restrict__ ot) {
  int gid = blockIdx.x * 256 + threadIdx.x;          // grid 1152 -> 294912 chunks of 8
  int n = gid >> 5, c8 = gid & 31;
  int b = n / S, s = n - b * S;
  int h = c8 >> 2;
  float l0 = lsum[(size_t)((b * 8 + h) * 2 + 0) * S + s];
  float l1 = lsum[(size_t)((b * 8 + h) * 2 + 1) * S + s];
  float inv = __builtin_amdgcn_rcpf(l0 + l1);
  bf16x8 a = *(const bf16x8*)&otP[(size_t)n * 256 + c8 * 8];
  bf16x8 bb = *(const bf16x8*)&otP[(size_t)9216 * 256 + (size_t)n * 256 + c8 * 8];
  bf16x8 o;
  #pragma unroll
  for (int e = 0; e < 8; ++e)
    o[e] = (short)f2bf((bf2f((u16)a[e]) + bf2f((u16)bb[e])) * inv);
  *(bf16x8*)&ot[(size_t)n * 256 + c8 * 8] = o;
}

// ---------------- kernel 5: out projection + bias + residual ----------------
__global__ __launch_bounds__(256) void k_oproj(const u16* __restrict__ A,
                                               const u16* __restrict__ Bm,
                                               float* __restrict__ out,
                                               const float* __restrict__ bias,
                                               const float* __restrict__ resid) {
  __shared__ __align__(16) u16 As[2][64 * 32];
  __shared__ __align__(16) u16 Bs[2][64 * 32];
  int tid = threadIdx.x, lane = tid & 63, w = tid >> 6;
  int cb = lane & 15, q4 = lane >> 4;
  int m0 = blockIdx.y * 64, n0 = blockIdx.x * 64;

  const u16* gA0 = A  + (size_t)(m0 + (tid >> 2)) * 256 + (tid & 3) * 8;
  const u16* gB0 = Bm + (size_t)(n0 + (tid >> 2)) * 256 + (tid & 3) * 8;
  char* lA = (char*)&As[0][0] + (w << 10);
  char* lB = (char*)&Bs[0][0] + (w << 10);

  #define STAGE_O(buf, k0) do {                      \
    GLDS(gA0 + (k0), lA + (buf) * 4096);             \
    GLDS(gB0 + (k0), lB + (buf) * 4096);             \
  } while (0)

  f32x4 zero4 = {0.f, 0.f, 0.f, 0.f};
  f32x4 acc[4];
  for (int j = 0; j < 4; ++j) acc[j] = zero4;

  STAGE_O(0, 0);
  __syncthreads();
  for (int ks = 0; ks < 8; ++ks) {
    int cur = ks & 1;
    if (ks < 7) STAGE_O(cur ^ 1, (ks + 1) * 32);
    const u16* as = &As[cur][0];
    const u16* bs = &Bs[cur][0];
    bf16x8 af = *(const bf16x8*)&as[(w * 16 + cb) * 32 + 8 * q4];
    bf16x8 bfr[4];
    for (int j = 0; j < 4; ++j)
      bfr[j] = *(const bf16x8*)&bs[(j * 16 + cb) * 32 + 8 * q4];
    for (int j = 0; j < 4; ++j)
      acc[j] = __builtin_amdgcn_mfma_f32_16x16x32_bf16(af, bfr[j], acc[j], 0, 0, 0);
    __syncthreads();
  }

  for (int j = 0; j < 4; ++j)
    for (int r = 0; r < 4; ++r) {
      int o = m0 + w * 16 + q4 * 4 + r;
      int n = n0 + j * 16 + cb;
      int b = n / S, s2 = n % S;
      size_t gi = (size_t)(b * 256 + o) * S + s2;
      out[gi] = acc[j][r] + bias[o] + resid[gi];
    }
  #undef STAGE_O
}

// ---------------- host launch ----------------
extern "C" void kernel_launch(void* const* d_in, const int* in_sizes, int n_in,
                              void* d_out, int out_size, void* d_ws, size_t ws_size,
                              hipStream_t stream) {
  const float* input = (const float*)d_in[0];
  const float* gnw   = (const float*)d_in[1];
  const float* gnb   = (const float*)d_in[2];
  const float* wqkv  = (const float*)d_in[3];
  const float* wout  = (const float*)d_in[4];
  const float* bout  = (const float*)d_in[5];
  float* out = (float*)d_out;
  char* ws = (char*)d_ws;

  size_t o_wq  = 0;                                   // 768*256*2
  size_t o_wo  = o_wq + (size_t)768 * 256 * 2;        // 256*256*2
  size_t o_st  = o_wo + (size_t)256 * 256 * 2;        // stats
  size_t o_nt  = o_st + 1024;                         // 9216*256*2 (nt; later reused as ot)
  size_t o_qkt = o_nt + (size_t)9216 * 256 * 2;       // 9216*512*2
  size_t o_vt  = o_qkt + (size_t)9216 * 512 * 2;      // 256*9216*2
  size_t o_oP  = o_vt + (size_t)256 * 9216 * 2;       // 2 * 9216*256*2
  size_t o_ls  = o_oP + (size_t)2 * 9216 * 256 * 2;   // 64*2304*4

  u16*    wq_bf = (u16*)(ws + o_wq);
  u16*    wo_bf = (u16*)(ws + o_wo);
  float2* stats = (float2*)(ws + o_st);
  u16*    nt    = (u16*)(ws + o_nt);
  u16*    qkt   = (u16*)(ws + o_qkt);
  u16*    vt    = (u16*)(ws + o_vt);
  u16*    otP   = (u16*)(ws + o_oP);
  float*  lsum  = (float*)(ws + o_ls);
  u16*    otb   = (u16*)(ws + o_nt);                  // reuse nt region (dead after k_qkv)

  k_prep<<<1024, 256, 0, stream>>>(wqkv, wout, wq_bf, wo_bf);
  k_gnstats<<<64, 1024, 0, stream>>>(input, stats);
  k_gnnorm<<<576, 256, 0, stream>>>(input, gnw, gnb, stats, nt);
  k_qkv<<<dim3(72, 12), 256, 0, stream>>>(wq_bf, nt, qkt, vt);
  k_attn<<<2304, 256, 0, stream>>>(qkt, vt, otP, lsum);
  k_comb<<<1152, 256, 0, stream>>>(otP, lsum, otb);
  k_oproj<<<dim3(144, 4), 256, 0, stream>>>(wo_bf, otb, out, bout, input);
}

// Round 7
// 88.822 us; speedup vs baseline: 2.9102x; 1.0494x over previous
//
#include <hip/hip_runtime.h>
#include <hip/hip_bf16.h>
#include <stdint.h>

#define S    2304
#define CHN  256
#define BATCH 4
#define NKEYS 1152                  // keys per half (in-block 2-way split)
#define QS   0.09016844005556021f   // (1/16) * log2(e)

typedef __attribute__((ext_vector_type(8))) short bf16x8;
typedef __attribute__((ext_vector_type(4))) float f32x4;
typedef __attribute__((ext_vector_type(2))) uint32_t u32x2;
typedef __attribute__((ext_vector_type(4))) unsigned short u16x4;
typedef unsigned short u16;

#define AS1 __attribute__((address_space(1)))
#define AS3 __attribute__((address_space(3)))
#define GLDS(gptr, lptr) __builtin_amdgcn_global_load_lds((const AS1 void*)(gptr), (AS3 void*)(lptr), 16, 0, 0)

__device__ __forceinline__ u16 f2bf(float f) {
  union { float f; uint32_t u; } v; v.f = f;
  uint32_t u = v.u;
  u += 0x7fffu + ((u >> 16) & 1u);
  return (u16)(u >> 16);
}
__device__ __forceinline__ float bf2f(u16 h) {
  union { uint32_t u; float f; } v; v.u = ((uint32_t)h) << 16;
  return v.f;
}
__device__ __forceinline__ uint32_t pk_bf16(float a, float b) {
  union { __hip_bfloat162 h; uint32_t u; } cv;
  cv.h = __float22bfloat162_rn(make_float2(a, b));
  return cv.u;
}

// ---------------- kernel 0: convert weights to bf16 + zero stats ----------------
__global__ void k_prep(const float* __restrict__ wq, const float* __restrict__ wo,
                       u16* __restrict__ wq_bf, u16* __restrict__ wo_bf,
                       float* __restrict__ sraw) {
  int i = blockIdx.x * 256 + threadIdx.x;
  if (blockIdx.x == 0 && threadIdx.x < 128) sraw[threadIdx.x] = 0.f;
  if (i < 768 * 256) wq_bf[i] = f2bf(wq[i]);
  int j = i - 768 * 256;
  if (j >= 0 && j < 256 * 256) wo_bf[j] = f2bf(wo[j]);
}

// ---------------- kernel 1: GroupNorm raw sums (256 blocks, atomic combine) ----------------
// group = 36864 floats = 9216 float4; 4 parts x 2304 float4 each.
__global__ void k_gnstats(const float* __restrict__ x, float* __restrict__ sraw) {
  int blk = blockIdx.x;                              // 256 = 64 bg * 4 parts
  int bg = blk >> 2, part = blk & 3;
  const float4* p = (const float4*)(x + (size_t)bg * 36864) + part * 2304;
  float s = 0.f, ss = 0.f;
  for (int i = threadIdx.x; i < 2304; i += 256) {
    float4 v = p[i];
    s  += v.x + v.y + v.z + v.w;
    ss += v.x * v.x + v.y * v.y + v.z * v.z + v.w * v.w;
  }
  int lane = threadIdx.x & 63, wv = threadIdx.x >> 6;
  for (int m = 1; m < 64; m <<= 1) { s += __shfl_xor(s, m, 64); ss += __shfl_xor(ss, m, 64); }
  __shared__ float rs[4], rss[4];
  if (lane == 0) { rs[wv] = s; rss[wv] = ss; }
  __syncthreads();
  if (threadIdx.x == 0) {
    float S_ = rs[0] + rs[1] + rs[2] + rs[3];
    float SS = rss[0] + rss[1] + rss[2] + rss[3];
    atomicAdd(&sraw[bg * 2], S_);
    atomicAdd(&sraw[bg * 2 + 1], SS);
  }
}

// ---------------- kernel 2: normalize + transpose-write normed^T [n][c] bf16 ----------------
__global__ void k_gnnorm(const float* __restrict__ x, const float* __restrict__ w,
                         const float* __restrict__ bias, const float* __restrict__ sraw,
                         u16* __restrict__ nt) {
  int bid = blockIdx.x;                              // 576 = 4b * 36sblk * 4cq
  int b = bid / 144, r = bid % 144;
  int sblk = r >> 2, cq = r & 3;
  int t = threadIdx.x;
  int ni = t & 63, cgrp = t >> 6;
  int s = sblk * 64 + ni;
  int cbase = cq * 64 + cgrp * 16;
  int bgi = b * 16 + (cbase >> 4);
  float sx = sraw[bgi * 2], ssx = sraw[bgi * 2 + 1];
  float mean = sx * (1.f / 36864.f);
  float var  = ssx * (1.f / 36864.f) - mean * mean;
  float rstd = rsqrtf(var + 1e-5f);
  bf16x8 v0, v1;
  #pragma unroll
  for (int e = 0; e < 16; ++e) {
    int c = cbase + e;
    float val = x[(size_t)(b * 256 + c) * S + s];
    float xn = (val - mean) * rstd * w[c] + bias[c];
    if (e < 8) v0[e] = (short)f2bf(xn); else v1[e - 8] = (short)f2bf(xn);
  }
  u16* dst = nt + (size_t)(b * S + s) * 256 + cbase;
  *(bf16x8*)dst = v0;
  *(bf16x8*)(dst + 8) = v1;
}

// ---------------- kernel 3: QKV GEMM + fused transpose epilogue ----------------
__global__ __launch_bounds__(256) void k_qkv(const u16* __restrict__ A,
                                             const u16* __restrict__ Bm,
                                             u16* __restrict__ qkt,
                                             u16* __restrict__ vt) {
  __shared__ __align__(16) u16 As[2][64 * 32];
  __shared__ __align__(16) u16 Bs[2][128 * 32];
  int tid = threadIdx.x, lane = tid & 63, w = tid >> 6;
  int wr = w >> 1, wc = w & 1;
  int cb = lane & 15, q4 = lane >> 4;
  int m0 = blockIdx.y * 64, n0 = blockIdx.x * 128;

  const u16* gA0 = A  + (size_t)(m0 + (tid >> 2)) * 256 + (tid & 3) * 8;
  const u16* gB0 = Bm + (size_t)(n0 + (tid >> 2)) * 256 + (tid & 3) * 8;
  const u16* gB1 = gB0 + 64 * 256;
  char* lA = (char*)&As[0][0] + (w << 10);
  char* lB = (char*)&Bs[0][0] + (w << 10);

  #define STAGE_Q(buf, k0) do {                      \
    GLDS(gA0 + (k0), lA + (buf) * 4096);             \
    GLDS(gB0 + (k0), lB + (buf) * 8192);             \
    GLDS(gB1 + (k0), lB + (buf) * 8192 + 4096);      \
  } while (0)

  f32x4 zero4 = {0.f, 0.f, 0.f, 0.f};
  f32x4 acc[2][4];
  for (int i = 0; i < 2; ++i) for (int j = 0; j < 4; ++j) acc[i][j] = zero4;

  STAGE_Q(0, 0);
  __syncthreads();
  for (int ks = 0; ks < 8; ++ks) {
    int cur = ks & 1;
    if (ks < 7) STAGE_Q(cur ^ 1, (ks + 1) * 32);
    const u16* as = &As[cur][0];
    const u16* bs = &Bs[cur][0];
    bf16x8 af[2], bfr[4];
    for (int i = 0; i < 2; ++i)
      af[i]  = *(const bf16x8*)&as[(wr * 32 + i * 16 + cb) * 32 + 8 * q4];
    for (int j = 0; j < 4; ++j)
      bfr[j] = *(const bf16x8*)&bs[(wc * 64 + j * 16 + cb) * 32 + 8 * q4];
    for (int i = 0; i < 2; ++i)
      for (int j = 0; j < 4; ++j)
        acc[i][j] = __builtin_amdgcn_mfma_f32_16x16x32_bf16(af[i], bfr[j], acc[i][j], 0, 0, 0);
    __syncthreads();
  }

  for (int i = 0; i < 2; ++i)
    for (int j = 0; j < 4; ++j) {
      int ob = m0 + wr * 32 + i * 16 + q4 * 4;
      int n  = n0 + wc * 64 + j * 16 + cb;
      int h = ob / 96, oq = ob % 96;
      if (oq < 64) {
        float sc = (oq < 32) ? QS : 1.f;
        u16x4 pk;
        for (int r = 0; r < 4; ++r) pk[r] = f2bf(acc[i][j][r] * sc);
        *(u16x4*)&qkt[(size_t)n * 512 + h * 64 + oq] = pk;
      } else {
        for (int r = 0; r < 4; ++r)
          vt[(size_t)(h * 32 + oq - 64 + r) * 9216 + n] = f2bf(acc[i][j][r]);
      }
    }
  #undef STAGE_Q
}

// ---------------- kernel 4: flash attention, in-block split-K, 512 threads ----------------
// 8 waves = 4 q-subtiles x 2 key-halves. No-max softmax; l via ones-MFMA.
// Halves combine through LDS at the end -> final normalized ot directly.
__global__ __launch_bounds__(512) void k_attn(const u16* __restrict__ qkt,
                                              const u16* __restrict__ vt,
                                              u16* __restrict__ ot) {
  __shared__ __align__(16) u16 Ks[2][2][2048];       // [half][buf][64key*32d] swizzled
  __shared__ __align__(16) u16 Vd[2][2][2048];       // [half][buf][32d*64key] swizzled
  __shared__ __align__(16) u16 Ps[8][1024];          // per-wave P [16q][64key] swizzled
  __shared__ float Ls[8][16];                        // per-wave l[q]

  int tid = threadIdx.x, lane = tid & 63, w = tid >> 6;
  int cb = lane & 15, g4 = lane >> 4;
  int qw = w & 3, half = w >> 2;
  // XCD swizzle: 1152 = 8 XCD * 144; consecutive orig (same bh) -> same XCD
  int hw = blockIdx.x;
  int orig = (hw & 7) * 144 + (hw >> 3);
  int bh = orig / 36, qtile = orig % 36;
  int b = bh >> 3, h = bh & 7;
  int q0 = qtile * 64 + qw * 16;

  const u16* kbase = qkt + (size_t)(b * S) * 512 + h * 64 + 32 + (size_t)half * NKEYS * 512;
  const u16* vbase = vt + (size_t)(h * 32) * 9216 + (size_t)b * S + half * NKEYS;

  bf16x8 qf = *(const bf16x8*)&qkt[(size_t)(b * S + q0 + cb) * 512 + h * 64 + 8 * g4];
  bf16x8 vones;
  #pragma unroll
  for (int e = 0; e < 8; ++e) vones[e] = (short)0x3F80;   // bf16 1.0

  f32x4 zero4 = {0.f, 0.f, 0.f, 0.f};
  f32x4 acc_o[2]; acc_o[0] = zero4; acc_o[1] = zero4;
  f32x4 lacc4 = zero4;                                // l[q=4g4+r]

  int xk = (cb ^ (cb >> 2)) & 3;
  int sw7 = cb & 7;

  // hoisted LDS addresses (buf0; buf1 = +2048 u16 = 4096B)
  const u16* p_kf[4];
  #pragma unroll
  for (int k4 = 0; k4 < 4; ++k4)
    p_kf[k4] = &Ks[half][0][(16 * k4 + cb) * 32 + ((g4 ^ xk) * 8)];
  u16* p_pw[4];
  #pragma unroll
  for (int k4 = 0; k4 < 4; ++k4)
    p_pw[k4] = &Ps[w][cb * 64 + (((2 * k4 + (g4 >> 1)) ^ sw7) << 3) + ((g4 & 1) << 2)];
  const u16* p_pa[2];
  #pragma unroll
  for (int kk = 0; kk < 2; ++kk)
    p_pa[kk] = &Ps[w][cb * 64 + (((4 * kk + g4) ^ sw7) << 3)];
  const u16* p_vb[2][2];
  #pragma unroll
  for (int jd = 0; jd < 2; ++jd)
    #pragma unroll
    for (int kk = 0; kk < 2; ++kk)
      p_vb[jd][kk] = &Vd[half][0][(16 * jd + cb) * 64 + (((4 * kk + g4) ^ sw7) << 3)];

  // staging: per-half sources, pre-swizzled; tloc = position within the half's 4 waves
  int tloc = tid & 255;
  int krow = tloc >> 2, kch = (tloc & 3) ^ ((krow ^ (krow >> 2)) & 3);
  int vrow = tloc >> 3, vch = (tloc & 7) ^ (vrow & 7);
  const u16* gK = kbase + (size_t)krow * 512 + kch * 8;
  const u16* gV = vbase + (size_t)vrow * 9216 + vch * 8;
  char* ldsK = (char*)&Ks[half][0][0] + (qw << 10);
  char* ldsV = (char*)&Vd[half][0][0] + (qw << 10);

  #define STAGE_A(buf) do {                          \
    GLDS(gK, ldsK + (buf) * 4096);                   \
    GLDS(gV, ldsV + (buf) * 4096);                   \
    gK += 64 * 512; gV += 64;                        \
  } while (0)

  #define TILE(buf, pf) do {                                                   \
    if (pf) STAGE_A(buf ^ 1);                                                  \
    bf16x8 kf[4];                                                              \
    _Pragma("unroll")                                                          \
    for (int k4 = 0; k4 < 4; ++k4)                                             \
      kf[k4] = *(const bf16x8*)(p_kf[k4] + (buf) * 2048);                      \
    f32x4 pacc[4];                                                             \
    __builtin_amdgcn_s_setprio(1);                                             \
    _Pragma("unroll")                                                          \
    for (int k4 = 0; k4 < 4; ++k4)                                             \
      pacc[k4] = __builtin_amdgcn_mfma_f32_16x16x32_bf16(kf[k4], qf, zero4, 0, 0, 0); \
    __builtin_amdgcn_s_setprio(0);                                             \
    _Pragma("unroll")                                                          \
    for (int k4 = 0; k4 < 4; ++k4) {                                           \
      f32x4 p = pacc[k4];                                                      \
      float e0 = __builtin_amdgcn_exp2f(p[0]);                                 \
      float e1 = __builtin_amdgcn_exp2f(p[1]);                                 \
      float e2 = __builtin_amdgcn_exp2f(p[2]);                                 \
      float e3 = __builtin_amdgcn_exp2f(p[3]);                                 \
      u32x2 pk = { pk_bf16(e0, e1), pk_bf16(e2, e3) };                         \
      *(u32x2*)p_pw[k4] = pk;                                                  \
    }                                                                          \
    asm volatile("s_waitcnt lgkmcnt(0)" ::: "memory");                         \
    __builtin_amdgcn_sched_barrier(0);                                         \
    __builtin_amdgcn_s_setprio(1);                                             \
    bf16x8 pa[2];                                                              \
    _Pragma("unroll")                                                          \
    for (int kk = 0; kk < 2; ++kk)                                             \
      pa[kk] = *(const bf16x8*)p_pa[kk];                                       \
    lacc4 = __builtin_amdgcn_mfma_f32_16x16x32_bf16(pa[0], vones, lacc4, 0, 0, 0); \
    lacc4 = __builtin_amdgcn_mfma_f32_16x16x32_bf16(pa[1], vones, lacc4, 0, 0, 0); \
    _Pragma("unroll")                                                          \
    for (int jd = 0; jd < 2; ++jd)                                             \
      _Pragma("unroll")                                                        \
      for (int kk = 0; kk < 2; ++kk) {                                         \
        bf16x8 vb = *(const bf16x8*)(p_vb[jd][kk] + (buf) * 2048);             \
        acc_o[jd] = __builtin_amdgcn_mfma_f32_16x16x32_bf16(pa[kk], vb, acc_o[jd], 0, 0, 0); \
      }                                                                        \
    __builtin_amdgcn_s_setprio(0);                                             \
    __syncthreads();                                                           \
  } while (0)

  STAGE_A(0);
  __syncthreads();
  for (int it = 0; it < 9; ++it) {                   // 18 tiles per half, unroll x2
    TILE(0, 1);
    TILE(1, it < 8);
  }

  // ---- in-block split-K combine (through Ps scratch, now dead) ----
  // O scratch layout per wave: f32 [32 d][16 q]; lane writes d=cb+16jd, q=4g4..+3.
  float* PsF = (float*)&Ps[w][0];
  #pragma unroll
  for (int jd = 0; jd < 2; ++jd)
    *(f32x4*)&PsF[(cb + 16 * jd) * 16 + 4 * g4] = acc_o[jd];
  if (cb == 0)
    *(f32x4*)&Ls[w][4 * g4] = lacc4;                 // every lane holds l[4g4+r]
  __syncthreads();

  // wave w outputs d-range [half*16, half*16+16) for q-subtile qw
  const float* A0 = (const float*)&Ps[qw][0];
  const float* A1 = (const float*)&Ps[qw + 4][0];
  int dd = half * 16 + cb;
  f32x4 s0 = *(const f32x4*)&A0[dd * 16 + 4 * g4];
  f32x4 s1 = *(const f32x4*)&A1[dd * 16 + 4 * g4];
  f32x4 lt0 = *(const f32x4*)&Ls[qw][4 * g4];
  f32x4 lt1 = *(const f32x4*)&Ls[qw + 4][4 * g4];
  #pragma unroll
  for (int r = 0; r < 4; ++r) {
    float inv = __builtin_amdgcn_rcpf(lt0[r] + lt1[r]);
    int sq = q0 + 4 * g4 + r;
    ot[(size_t)(b * S + sq) * 256 + h * 32 + dd] = f2bf((s0[r] + s1[r]) * inv);
  }
  #undef STAGE_A
  #undef TILE
}

// ---------------- kernel 5: out projection + bias + residual ----------------
__global__ __launch_bounds__(256) void k_oproj(const u16* __restrict__ A,
                                               const u16* __restrict__ Bm,
                                               float* __restrict__ out,
                                               const float* __restrict__ bias,
                                               const float* __restrict__ resid) {
  __shared__ __align__(16) u16 As[2][64 * 32];
  __shared__ __align__(16) u16 Bs[2][64 * 32];
  int tid = threadIdx.x, lane = tid & 63, w = tid >> 6;
  int cb = lane & 15, q4 = lane >> 4;
  int m0 = blockIdx.y * 64, n0 = blockIdx.x * 64;

  const u16* gA0 = A  + (size_t)(m0 + (tid >> 2)) * 256 + (tid & 3) * 8;
  const u16* gB0 = Bm + (size_t)(n0 + (tid >> 2)) * 256 + (tid & 3) * 8;
  char* lA = (char*)&As[0][0] + (w << 10);
  char* lB = (char*)&Bs[0][0] + (w << 10);

  #define STAGE_O(buf, k0) do {                      \
    GLDS(gA0 + (k0), lA + (buf) * 4096);             \
    GLDS(gB0 + (k0), lB + (buf) * 4096);             \
  } while (0)

  f32x4 zero4 = {0.f, 0.f, 0.f, 0.f};
  f32x4 acc[4];
  for (int j = 0; j < 4; ++j) acc[j] = zero4;

  STAGE_O(0, 0);
  __syncthreads();
  for (int ks = 0; ks < 8; ++ks) {
    int cur = ks & 1;
    if (ks < 7) STAGE_O(cur ^ 1, (ks + 1) * 32);
    const u16* as = &As[cur][0];
    const u16* bs = &Bs[cur][0];
    bf16x8 af = *(const bf16x8*)&as[(w * 16 + cb) * 32 + 8 * q4];
    bf16x8 bfr[4];
    for (int j = 0; j < 4; ++j)
      bfr[j] = *(const bf16x8*)&bs[(j * 16 + cb) * 32 + 8 * q4];
    for (int j = 0; j < 4; ++j)
      acc[j] = __builtin_amdgcn_mfma_f32_16x16x32_bf16(af, bfr[j], acc[j], 0, 0, 0);
    __syncthreads();
  }

  for (int j = 0; j < 4; ++j)
    for (int r = 0; r < 4; ++r) {
      int o = m0 + w * 16 + q4 * 4 + r;
      int n = n0 + j * 16 + cb;
      int b = n / S, s2 = n % S;
      size_t gi = (size_t)(b * 256 + o) * S + s2;
      out[gi] = acc[j][r] + bias[o] + resid[gi];
    }
  #undef STAGE_O
}

// ---------------- host launch ----------------
extern "C" void kernel_launch(void* const* d_in, const int* in_sizes, int n_in,
                              void* d_out, int out_size, void* d_ws, size_t ws_size,
                              hipStream_t stream) {
  const float* input = (const float*)d_in[0];
  const float* gnw   = (const float*)d_in[1];
  const float* gnb   = (const float*)d_in[2];
  const float* wqkv  = (const float*)d_in[3];
  const float* wout  = (const float*)d_in[4];
  const float* bout  = (const float*)d_in[5];
  float* out = (float*)d_out;
  char* ws = (char*)d_ws;

  size_t o_wq  = 0;                                   // 768*256*2
  size_t o_wo  = o_wq + (size_t)768 * 256 * 2;        // 256*256*2
  size_t o_st  = o_wo + (size_t)256 * 256 * 2;        // raw stats (512B, pad to 1KB)
  size_t o_nt  = o_st + 1024;                         // 9216*256*2 (nt; reused as ot)
  size_t o_qkt = o_nt + (size_t)9216 * 256 * 2;       // 9216*512*2
  size_t o_vt  = o_qkt + (size_t)9216 * 512 * 2;      // 256*9216*2

  u16*    wq_bf = (u16*)(ws + o_wq);
  u16*    wo_bf = (u16*)(ws + o_wo);
  float*  sraw  = (float*)(ws + o_st);
  u16*    nt    = (u16*)(ws + o_nt);
  u16*    qkt   = (u16*)(ws + o_qkt);
  u16*    vt    = (u16*)(ws + o_vt);
  u16*    otb   = (u16*)(ws + o_nt);                  // reuse nt region (dead after k_qkv)

  k_prep<<<1024, 256, 0, stream>>>(wqkv, wout, wq_bf, wo_bf, sraw);
  k_gnstats<<<256, 256, 0, stream>>>(input, sraw);
  k_gnnorm<<<576, 256, 0, stream>>>(input, gnw, gnb, sraw, nt);
  k_qkv<<<dim3(72, 12), 256, 0, stream>>>(wq_bf, nt, qkt, vt);
  k_attn<<<1152, 512, 0, stream>>>(qkt, vt, otb);
  k_oproj<<<dim3(144, 4), 256, 0, stream>>>(wo_bf, otb, out, bout, input);
}

// Round 8
// 88.028 us; speedup vs baseline: 2.9365x; 1.0090x over previous
//
#include <hip/hip_runtime.h>
#include <hip/hip_bf16.h>
#include <stdint.h>

#define S    2304
#define CHN  256
#define BATCH 4
#define NKEYS 1152                  // keys per half (in-block 2-way split)
#define QS   0.09016844005556021f   // (1/16) * log2(e)

typedef __attribute__((ext_vector_type(8))) short bf16x8;
typedef __attribute__((ext_vector_type(4))) short bf16x4;
typedef __attribute__((ext_vector_type(4))) float f32x4;
typedef __attribute__((ext_vector_type(4))) uint32_t u32x4;
typedef __attribute__((ext_vector_type(4))) unsigned short u16x4;
typedef unsigned short u16;

#define AS1 __attribute__((address_space(1)))
#define AS3 __attribute__((address_space(3)))
#define GLDS(gptr, lptr) __builtin_amdgcn_global_load_lds((const AS1 void*)(gptr), (AS3 void*)(lptr), 16, 0, 0)

__device__ __forceinline__ u16 f2bf(float f) {
  union { float f; uint32_t u; } v; v.f = f;
  uint32_t u = v.u;
  u += 0x7fffu + ((u >> 16) & 1u);
  return (u16)(u >> 16);
}
__device__ __forceinline__ float bf2f(u16 h) {
  union { uint32_t u; float f; } v; v.u = ((uint32_t)h) << 16;
  return v.f;
}
__device__ __forceinline__ uint32_t pk_bf16(float a, float b) {
  union { __hip_bfloat162 h; uint32_t u; } cv;
  cv.h = __float22bfloat162_rn(make_float2(a, b));
  return cv.u;
}

// ---------------- kernel 0: convert weights to bf16 + zero stats ----------------
__global__ void k_prep(const float* __restrict__ wq, const float* __restrict__ wo,
                       u16* __restrict__ wq_bf, u16* __restrict__ wo_bf,
                       float* __restrict__ sraw) {
  int i = blockIdx.x * 256 + threadIdx.x;
  if (blockIdx.x == 0 && threadIdx.x < 128) sraw[threadIdx.x] = 0.f;
  if (i < 768 * 256) wq_bf[i] = f2bf(wq[i]);
  int j = i - 768 * 256;
  if (j >= 0 && j < 256 * 256) wo_bf[j] = f2bf(wo[j]);
}

// ---------------- kernel 1: GroupNorm raw sums (256 blocks, atomic combine) ----------------
// group = 36864 floats = 9216 float4; 4 parts x 2304 float4 each.
__global__ void k_gnstats(const float* __restrict__ x, float* __restrict__ sraw) {
  int blk = blockIdx.x;                              // 256 = 64 bg * 4 parts
  int bg = blk >> 2, part = blk & 3;
  const float4* p = (const float4*)(x + (size_t)bg * 36864) + part * 2304;
  float s = 0.f, ss = 0.f;
  for (int i = threadIdx.x; i < 2304; i += 256) {
    float4 v = p[i];
    s  += v.x + v.y + v.z + v.w;
    ss += v.x * v.x + v.y * v.y + v.z * v.z + v.w * v.w;
  }
  int lane = threadIdx.x & 63, wv = threadIdx.x >> 6;
  for (int m = 1; m < 64; m <<= 1) { s += __shfl_xor(s, m, 64); ss += __shfl_xor(ss, m, 64); }
  __shared__ float rs[4], rss[4];
  if (lane == 0) { rs[wv] = s; rss[wv] = ss; }
  __syncthreads();
  if (threadIdx.x == 0) {
    float S_ = rs[0] + rs[1] + rs[2] + rs[3];
    float SS = rss[0] + rss[1] + rss[2] + rss[3];
    atomicAdd(&sraw[bg * 2], S_);
    atomicAdd(&sraw[bg * 2 + 1], SS);
  }
}

// ---------------- kernel 2: normalize + transpose-write normed^T [n][c] bf16 ----------------
__global__ void k_gnnorm(const float* __restrict__ x, const float* __restrict__ w,
                         const float* __restrict__ bias, const float* __restrict__ sraw,
                         u16* __restrict__ nt) {
  int bid = blockIdx.x;                              // 576 = 4b * 36sblk * 4cq
  int b = bid / 144, r = bid % 144;
  int sblk = r >> 2, cq = r & 3;
  int t = threadIdx.x;
  int ni = t & 63, cgrp = t >> 6;
  int s = sblk * 64 + ni;
  int cbase = cq * 64 + cgrp * 16;
  int bgi = b * 16 + (cbase >> 4);
  float sx = sraw[bgi * 2], ssx = sraw[bgi * 2 + 1];
  float mean = sx * (1.f / 36864.f);
  float var  = ssx * (1.f / 36864.f) - mean * mean;
  float rstd = rsqrtf(var + 1e-5f);
  bf16x8 v0, v1;
  #pragma unroll
  for (int e = 0; e < 16; ++e) {
    int c = cbase + e;
    float val = x[(size_t)(b * 256 + c) * S + s];
    float xn = (val - mean) * rstd * w[c] + bias[c];
    if (e < 8) v0[e] = (short)f2bf(xn); else v1[e - 8] = (short)f2bf(xn);
  }
  u16* dst = nt + (size_t)(b * S + s) * 256 + cbase;
  *(bf16x8*)dst = v0;
  *(bf16x8*)(dst + 8) = v1;
}

// ---------------- kernel 3: QKV GEMM + fused transpose epilogue ----------------
__global__ __launch_bounds__(256) void k_qkv(const u16* __restrict__ A,
                                             const u16* __restrict__ Bm,
                                             u16* __restrict__ qkt,
                                             u16* __restrict__ vt) {
  __shared__ __align__(16) u16 As[2][64 * 32];
  __shared__ __align__(16) u16 Bs[2][128 * 32];
  int tid = threadIdx.x, lane = tid & 63, w = tid >> 6;
  int wr = w >> 1, wc = w & 1;
  int cb = lane & 15, q4 = lane >> 4;
  int m0 = blockIdx.y * 64, n0 = blockIdx.x * 128;

  const u16* gA0 = A  + (size_t)(m0 + (tid >> 2)) * 256 + (tid & 3) * 8;
  const u16* gB0 = Bm + (size_t)(n0 + (tid >> 2)) * 256 + (tid & 3) * 8;
  const u16* gB1 = gB0 + 64 * 256;
  char* lA = (char*)&As[0][0] + (w << 10);
  char* lB = (char*)&Bs[0][0] + (w << 10);

  #define STAGE_Q(buf, k0) do {                      \
    GLDS(gA0 + (k0), lA + (buf) * 4096);             \
    GLDS(gB0 + (k0), lB + (buf) * 8192);             \
    GLDS(gB1 + (k0), lB + (buf) * 8192 + 4096);      \
  } while (0)

  f32x4 zero4 = {0.f, 0.f, 0.f, 0.f};
  f32x4 acc[2][4];
  for (int i = 0; i < 2; ++i) for (int j = 0; j < 4; ++j) acc[i][j] = zero4;

  STAGE_Q(0, 0);
  __syncthreads();
  for (int ks = 0; ks < 8; ++ks) {
    int cur = ks & 1;
    if (ks < 7) STAGE_Q(cur ^ 1, (ks + 1) * 32);
    const u16* as = &As[cur][0];
    const u16* bs = &Bs[cur][0];
    bf16x8 af[2], bfr[4];
    for (int i = 0; i < 2; ++i)
      af[i]  = *(const bf16x8*)&as[(wr * 32 + i * 16 + cb) * 32 + 8 * q4];
    for (int j = 0; j < 4; ++j)
      bfr[j] = *(const bf16x8*)&bs[(wc * 64 + j * 16 + cb) * 32 + 8 * q4];
    for (int i = 0; i < 2; ++i)
      for (int j = 0; j < 4; ++j)
        acc[i][j] = __builtin_amdgcn_mfma_f32_16x16x32_bf16(af[i], bfr[j], acc[i][j], 0, 0, 0);
    __syncthreads();
  }

  for (int i = 0; i < 2; ++i)
    for (int j = 0; j < 4; ++j) {
      int ob = m0 + wr * 32 + i * 16 + q4 * 4;
      int n  = n0 + wc * 64 + j * 16 + cb;
      int h = ob / 96, oq = ob % 96;
      if (oq < 64) {
        float sc = (oq < 32) ? QS : 1.f;
        u16x4 pk;
        for (int r = 0; r < 4; ++r) pk[r] = f2bf(acc[i][j][r] * sc);
        *(u16x4*)&qkt[(size_t)n * 512 + h * 64 + oq] = pk;
      } else {
        for (int r = 0; r < 4; ++r)
          vt[(size_t)(h * 32 + oq - 64 + r) * 9216 + n] = f2bf(acc[i][j][r]);
      }
    }
  #undef STAGE_Q
}

// ---------------- kernel 4: flash attention, in-block split-K, in-register P ----------------
// 8 waves = 4 q-subtiles x 2 key-halves. No-max softmax; l via ones-MFMA.
// PV uses a key permutation so each lane's exp outputs ARE its A-fragments:
//   perm(32kk+8g+j) = 32kk + 16*(j>>2) + 4g + (j&3); V read in perm order (2x b64).
__global__ __launch_bounds__(512) void k_attn(const u16* __restrict__ qkt,
                                              const u16* __restrict__ vt,
                                              u16* __restrict__ ot) {
  __shared__ __align__(16) u16 Ks[2][2][2048];       // [half][buf][64key*32d] swizzled
  __shared__ __align__(16) u16 Vd[2][2][2048];       // [half][buf][32d*64key] swizzled
  __shared__ float Ls[8][16];                        // per-wave l[q]

  int tid = threadIdx.x, lane = tid & 63, w = tid >> 6;
  int cb = lane & 15, g4 = lane >> 4;
  int qw = w & 3, half = w >> 2;
  // XCD swizzle: 1152 = 8 XCD * 144
  int hw = blockIdx.x;
  int orig = (hw & 7) * 144 + (hw >> 3);
  int bh = orig / 36, qtile = orig % 36;
  int b = bh >> 3, h = bh & 7;
  int q0 = qtile * 64 + qw * 16;

  const u16* kbase = qkt + (size_t)(b * S) * 512 + h * 64 + 32 + (size_t)half * NKEYS * 512;
  const u16* vbase = vt + (size_t)(h * 32) * 9216 + (size_t)b * S + half * NKEYS;

  bf16x8 qf = *(const bf16x8*)&qkt[(size_t)(b * S + q0 + cb) * 512 + h * 64 + 8 * g4];
  bf16x8 vones;
  #pragma unroll
  for (int e = 0; e < 8; ++e) vones[e] = (short)0x3F80;   // bf16 1.0

  f32x4 zero4 = {0.f, 0.f, 0.f, 0.f};
  f32x4 acc_o[2]; acc_o[0] = zero4; acc_o[1] = zero4;
  f32x4 lacc4 = zero4;                                // l[q=4g4+r]

  int xk = (cb ^ (cb >> 2)) & 3;

  // hoisted LDS addresses (buf0; buf1 = +2048 u16 = 4096B)
  const u16* p_k = &Ks[half][0][cb * 32 + ((g4 ^ xk) * 8)];            // k4: +512 u16
  const u16* p_v[2][2];                                                // [kk][h2]; jd: +1024 u16
  #pragma unroll
  for (int kk = 0; kk < 2; ++kk)
    #pragma unroll
    for (int h2 = 0; h2 < 2; ++h2) {
      int chunk = 4 * kk + 2 * h2 + (g4 >> 1);
      p_v[kk][h2] = &Vd[half][0][cb * 64 + ((chunk ^ (cb & 7)) << 3) + 4 * (g4 & 1)];
    }

  // staging: per-half sources, pre-swizzled; tloc = position within the half's 4 waves
  int tloc = tid & 255;
  int krow = tloc >> 2, kch = (tloc & 3) ^ ((krow ^ (krow >> 2)) & 3);
  int vrow = tloc >> 3, vch = (tloc & 7) ^ (vrow & 7);
  const u16* gK = kbase + (size_t)krow * 512 + kch * 8;
  const u16* gV = vbase + (size_t)vrow * 9216 + vch * 8;
  char* ldsK = (char*)&Ks[half][0][0] + (qw << 10);
  char* ldsV = (char*)&Vd[half][0][0] + (qw << 10);

  #define STAGE_A(buf) do {                          \
    GLDS(gK, ldsK + (buf) * 4096);                   \
    GLDS(gV, ldsV + (buf) * 4096);                   \
    gK += 64 * 512; gV += 64;                        \
  } while (0)

  #define TILE(buf, pf) do {                                                   \
    if (pf) STAGE_A(buf ^ 1);                                                  \
    bf16x8 kf[4];                                                              \
    _Pragma("unroll")                                                          \
    for (int k4 = 0; k4 < 4; ++k4)                                             \
      kf[k4] = *(const bf16x8*)(p_k + (buf) * 2048 + k4 * 512);                \
    bf16x4 vlo[2][2], vhi[2][2];  /* [jd][kk] */                               \
    _Pragma("unroll")                                                          \
    for (int jd = 0; jd < 2; ++jd)                                             \
      _Pragma("unroll")                                                        \
      for (int kk = 0; kk < 2; ++kk) {                                         \
        vlo[jd][kk] = *(const bf16x4*)(p_v[kk][0] + (buf) * 2048 + jd * 1024); \
        vhi[jd][kk] = *(const bf16x4*)(p_v[kk][1] + (buf) * 2048 + jd * 1024); \
      }                                                                        \
    f32x4 pacc[4];                                                             \
    __builtin_amdgcn_s_setprio(1);                                             \
    _Pragma("unroll")                                                          \
    for (int k4 = 0; k4 < 4; ++k4)                                             \
      pacc[k4] = __builtin_amdgcn_mfma_f32_16x16x32_bf16(kf[k4], qf, zero4, 0, 0, 0); \
    __builtin_amdgcn_s_setprio(0);                                             \
    uint32_t W01[4], W23[4];                                                   \
    _Pragma("unroll")                                                          \
    for (int k4 = 0; k4 < 4; ++k4) {                                           \
      f32x4 p = pacc[k4];                                                      \
      float e0 = __builtin_amdgcn_exp2f(p[0]);                                 \
      float e1 = __builtin_amdgcn_exp2f(p[1]);                                 \
      float e2 = __builtin_amdgcn_exp2f(p[2]);                                 \
      float e3 = __builtin_amdgcn_exp2f(p[3]);                                 \
      W01[k4] = pk_bf16(e0, e1);                                               \
      W23[k4] = pk_bf16(e2, e3);                                               \
    }                                                                          \
    union { u32x4 u; bf16x8 v; } pu0, pu1;                                     \
    pu0.u = (u32x4){W01[0], W23[0], W01[1], W23[1]};                           \
    pu1.u = (u32x4){W01[2], W23[2], W01[3], W23[3]};                           \
    __builtin_amdgcn_s_setprio(1);                                             \
    lacc4 = __builtin_amdgcn_mfma_f32_16x16x32_bf16(pu0.v, vones, lacc4, 0, 0, 0); \
    lacc4 = __builtin_amdgcn_mfma_f32_16x16x32_bf16(pu1.v, vones, lacc4, 0, 0, 0); \
    _Pragma("unroll")                                                          \
    for (int jd = 0; jd < 2; ++jd) {                                           \
      bf16x8 vb0 = __builtin_shufflevector(vlo[jd][0], vhi[jd][0], 0,1,2,3,4,5,6,7); \
      bf16x8 vb1 = __builtin_shufflevector(vlo[jd][1], vhi[jd][1], 0,1,2,3,4,5,6,7); \
      acc_o[jd] = __builtin_amdgcn_mfma_f32_16x16x32_bf16(pu0.v, vb0, acc_o[jd], 0, 0, 0); \
      acc_o[jd] = __builtin_amdgcn_mfma_f32_16x16x32_bf16(pu1.v, vb1, acc_o[jd], 0, 0, 0); \
    }                                                                          \
    __builtin_amdgcn_s_setprio(0);                                             \
    __syncthreads();                                                           \
  } while (0)

  STAGE_A(0);
  __syncthreads();
  for (int it = 0; it < 9; ++it) {                   // 18 tiles per half, unroll x2
    TILE(0, 1);
    TILE(1, it < 8);
  }

  // ---- in-block split-K combine (scratch overlays Ks, dead after the loop) ----
  // Per wave: f32 [32 d][16 q]; lane writes d=cb+16jd, q=4g4..+3.
  float* OsF = (float*)&Ks[0][0][0];                 // 4096 f32; 8 waves x 512
  float* myO = OsF + w * 512;
  #pragma unroll
  for (int jd = 0; jd < 2; ++jd)
    *(f32x4*)&myO[(cb + 16 * jd) * 16 + 4 * g4] = acc_o[jd];
  if (cb == 0)
    *(f32x4*)&Ls[w][4 * g4] = lacc4;                 // every lane holds l[4g4+r]
  __syncthreads();

  // wave w outputs d-range [half*16, half*16+16) for q-subtile qw
  const float* A0 = OsF + qw * 512;
  const float* A1 = OsF + (qw + 4) * 512;
  int dd = half * 16 + cb;
  f32x4 s0 = *(const f32x4*)&A0[dd * 16 + 4 * g4];
  f32x4 s1 = *(const f32x4*)&A1[dd * 16 + 4 * g4];
  f32x4 lt0 = *(const f32x4*)&Ls[qw][4 * g4];
  f32x4 lt1 = *(const f32x4*)&Ls[qw + 4][4 * g4];
  #pragma unroll
  for (int r = 0; r < 4; ++r) {
    float inv = __builtin_amdgcn_rcpf(lt0[r] + lt1[r]);
    int sq = q0 + 4 * g4 + r;
    ot[(size_t)(b * S + sq) * 256 + h * 32 + dd] = f2bf((s0[r] + s1[r]) * inv);
  }
  #undef STAGE_A
  #undef TILE
}

// ---------------- kernel 5: out projection + bias + residual ----------------
__global__ __launch_bounds__(256) void k_oproj(const u16* __restrict__ A,
                                               const u16* __restrict__ Bm,
                                               float* __restrict__ out,
                                               const float* __restrict__ bias,
                                               const float* __restrict__ resid) {
  __shared__ __align__(16) u16 As[2][64 * 32];
  __shared__ __align__(16) u16 Bs[2][64 * 32];
  int tid = threadIdx.x, lane = tid & 63, w = tid >> 6;
  int cb = lane & 15, q4 = lane >> 4;
  int m0 = blockIdx.y * 64, n0 = blockIdx.x * 64;

  const u16* gA0 = A  + (size_t)(m0 + (tid >> 2)) * 256 + (tid & 3) * 8;
  const u16* gB0 = Bm + (size_t)(n0 + (tid >> 2)) * 256 + (tid & 3) * 8;
  char* lA = (char*)&As[0][0] + (w << 10);
  char* lB = (char*)&Bs[0][0] + (w << 10);

  #define STAGE_O(buf, k0) do {                      \
    GLDS(gA0 + (k0), lA + (buf) * 4096);             \
    GLDS(gB0 + (k0), lB + (buf) * 4096);             \
  } while (0)

  f32x4 zero4 = {0.f, 0.f, 0.f, 0.f};
  f32x4 acc[4];
  for (int j = 0; j < 4; ++j) acc[j] = zero4;

  STAGE_O(0, 0);
  __syncthreads();
  for (int ks = 0; ks < 8; ++ks) {
    int cur = ks & 1;
    if (ks < 7) STAGE_O(cur ^ 1, (ks + 1) * 32);
    const u16* as = &As[cur][0];
    const u16* bs = &Bs[cur][0];
    bf16x8 af = *(const bf16x8*)&as[(w * 16 + cb) * 32 + 8 * q4];
    bf16x8 bfr[4];
    for (int j = 0; j < 4; ++j)
      bfr[j] = *(const bf16x8*)&bs[(j * 16 + cb) * 32 + 8 * q4];
    for (int j = 0; j < 4; ++j)
      acc[j] = __builtin_amdgcn_mfma_f32_16x16x32_bf16(af, bfr[j], acc[j], 0, 0, 0);
    __syncthreads();
  }

  for (int j = 0; j < 4; ++j)
    for (int r = 0; r < 4; ++r) {
      int o = m0 + w * 16 + q4 * 4 + r;
      int n = n0 + j * 16 + cb;
      int b = n / S, s2 = n % S;
      size_t gi = (size_t)(b * 256 + o) * S + s2;
      out[gi] = acc[j][r] + bias[o] + resid[gi];
    }
  #undef STAGE_O
}

// ---------------- host launch ----------------
extern "C" void kernel_launch(void* const* d_in, const int* in_sizes, int n_in,
                              void* d_out, int out_size, void* d_ws, size_t ws_size,
                              hipStream_t stream) {
  const float* input = (const float*)d_in[0];
  const float* gnw   = (const float*)d_in[1];
  const float* gnb   = (const float*)d_in[2];
  const float* wqkv  = (const float*)d_in[3];
  const float* wout  = (const float*)d_in[4];
  const float* bout  = (const float*)d_in[5];
  float* out = (float*)d_out;
  char* ws = (char*)d_ws;

  size_t o_wq  = 0;                                   // 768*256*2
  size_t o_wo  = o_wq + (size_t)768 * 256 * 2;        // 256*256*2
  size_t o_st  = o_wo + (size_t)256 * 256 * 2;        // raw stats
  size_t o_nt  = o_st + 1024;                         // 9216*256*2 (nt; reused as ot)
  size_t o_qkt = o_nt + (size_t)9216 * 256 * 2;       // 9216*512*2
  size_t o_vt  = o_qkt + (size_t)9216 * 512 * 2;      // 256*9216*2

  u16*    wq_bf = (u16*)(ws + o_wq);
  u16*    wo_bf = (u16*)(ws + o_wo);
  float*  sraw  = (float*)(ws + o_st);
  u16*    nt    = (u16*)(ws + o_nt);
  u16*    qkt   = (u16*)(ws + o_qkt);
  u16*    vt    = (u16*)(ws + o_vt);
  u16*    otb   = (u16*)(ws + o_nt);                  // reuse nt region (dead after k_qkv)

  k_prep<<<1024, 256, 0, stream>>>(wqkv, wout, wq_bf, wo_bf, sraw);
  k_gnstats<<<256, 256, 0, stream>>>(input, sraw);
  k_gnnorm<<<576, 256, 0, stream>>>(input, gnw, gnb, sraw, nt);
  k_qkv<<<dim3(72, 12), 256, 0, stream>>>(wq_bf, nt, qkt, vt);
  k_attn<<<1152, 512, 0, stream>>>(qkt, vt, otb);
  k_oproj<<<dim3(144, 4), 256, 0, stream>>>(wo_bf, otb, out, bout, input);
}